// Round 7
// baseline (711.221 us; speedup 1.0000x reference)
//
#include <hip/hip_runtime.h>

typedef unsigned short u16;
typedef unsigned int   u32;
typedef __bf16  bf16x8 __attribute__((ext_vector_type(8)));
typedef float   f32x4  __attribute__((ext_vector_type(4)));
typedef float   f32x16 __attribute__((ext_vector_type(16)));

__device__ __forceinline__ float bf2f(u16 u) {
    u32 v = ((u32)u) << 16;
    return __builtin_bit_cast(float, v);
}
__device__ __forceinline__ u16 f2bf(float f) {
    u32 u = __builtin_bit_cast(u32, f);
    return (u16)((u + 0x7FFFu + ((u >> 16) & 1u)) >> 16);   // RNE
}
__device__ __forceinline__ float ldf(const void* p, long i, int f32) {
    return f32 ? ((const float*)p)[i] : bf2f(((const u16*)p)[i]);
}
__device__ __forceinline__ int is_f32(const u32* im) {
    return im[0] == 0x43E00000u;   // 448.0f fp32 vs packed bf16 (0x43E043E0)
}
// async global->LDS, 16B per lane (LDS dst = wave-uniform base + lane*16)
__device__ __forceinline__ void gl2lds16(const u16* g, u16* l) {
    __builtin_amdgcn_global_load_lds(
        (const __attribute__((address_space(1))) void*)g,
        (__attribute__((address_space(3))) void*)l, 16, 0, 0);
}

// ------------------------------------------- zero only the pad halo of xpad
__global__ void zero_halo(u16* __restrict__ xpad)
{
    int i = blockIdx.x * 256 + threadIdx.x;
    if (i < 230400) {                       // t in {0,17}: 2b*2t*900*64
        int c8 = i & 63; int pos = i >> 6;
        int p = pos % 900; pos /= 900;
        int t = (pos & 1) * 17; int b = pos >> 1;
        long o = (((long)(b * 18 + t) * 900) + p) * 512 + c8 * 8;
        *(uint4*)&xpad[o] = uint4{0u, 0u, 0u, 0u};
        return;
    }
    i -= 230400;
    if (i < 122880) {                       // t 1..16, h in {0,29}: 2*16*2*30*64
        int c8 = i & 63; int pos = i >> 6;
        int w = pos % 30; pos /= 30;
        int h = (pos & 1) * 29; pos >>= 1;
        int t = pos % 16 + 1; int b = pos / 16;
        long o = ((((long)(b * 18 + t) * 30 + h) * 30) + w) * 512 + c8 * 8;
        *(uint4*)&xpad[o] = uint4{0u, 0u, 0u, 0u};
        return;
    }
    i -= 122880;
    if (i < 114688) {                       // t 1..16, h 1..28, w in {0,29}
        int c8 = i & 63; int pos = i >> 6;
        int w = (pos & 1) * 29; pos >>= 1;
        int h = pos % 28 + 1; pos /= 28;
        int t = pos % 16 + 1; int b = pos / 16;
        long o = ((((long)(b * 18 + t) * 30 + h) * 30) + w) * 512 + c8 * 8;
        *(uint4*)&xpad[o] = uint4{0u, 0u, 0u, 0u};
    }
}

// ------------------------------------------------- pad+transpose base_feat
__global__ void pad_fill(const void* __restrict__ src, u16* __restrict__ xpad,
                         const u32* __restrict__ im)
{
    const int f32 = is_f32(im);
    __shared__ u16 lds[56 * 40];
    int blk = blockIdx.x;
    const int h2  = blk % 14;  blk /= 14;
    const int c32 = blk & 15;  blk >>= 4;
    const int t   = blk & 15;
    const int b   = blk >> 4;
    const int tid = threadIdx.x;
    const long sbase = ((long)(b * 512 + c32 * 32) * 16 + t) * 784 + h2 * 56;
    #pragma unroll
    for (int it = tid; it < 1792; it += 256) {
        const int c = it / 56, p = it - c * 56;
        float v = f32 ? ((const float*)src)[sbase + (long)c * 12544 + p]
                      : bf2f(((const u16*)src)[sbase + (long)c * 12544 + p]);
        lds[p * 40 + c] = f2bf(v);
    }
    __syncthreads();
    if (tid < 224) {
        const int p = tid >> 2, g = tid & 3;
        const int h = h2 * 2 + p / 28, w = p % 28;
        const long o = (((long)(b * 18 + t + 1) * 30 + h + 1) * 30 + (w + 1)) * 512
                       + c32 * 32 + g * 8;
        *(uint4*)&xpad[o] = *(const uint4*)&lds[p * 40 + g * 8];
    }
}

// ------------------------------------------------- W_conv [O][I][27] -> Wt[27][O][I]
__global__ void wt_transform(const void* __restrict__ wconv, u16* __restrict__ wt,
                             const u32* __restrict__ im)
{
    const int f32 = is_f32(im);
    __shared__ u16 lds[256 * 28];
    const int tid = threadIdx.x;
    const int pair_base = blockIdx.x * 256;
    const long s0 = (long)pair_base * 27;
    for (int it = tid; it < 256 * 27; it += 256) {
        const int p = it / 27, o = it - p * 27;
        float v = f32 ? ((const float*)wconv)[s0 + it]
                      : bf2f(((const u16*)wconv)[s0 + it]);
        lds[p * 28 + o] = f2bf(v);
    }
    __syncthreads();
    #pragma unroll
    for (int off = 0; off < 27; ++off)
        wt[(long)off * 262144 + pair_base + tid] = lds[tid * 28 + off];
}

// ------------------------------------------------- head weights + biases (merged)
__global__ void cvt_all(const void* s0, const void* s1, const void* s2,
                        const void* s3, const void* s4,
                        const void* b0, const void* b1, const void* b2,
                        const void* b3, const void* b4, const void* b5,
                        u16* __restrict__ whd, float* __restrict__ bfs,
                        const u32* __restrict__ im)
{
    const int f32 = is_f32(im);
    int i = blockIdx.x * 256 + threadIdx.x;
    if (i < 1244160) {
        const void* s; long j;
        if      (i < 15360)   { s = s0; j = i; }
        else if (i < 506880)  { s = s1; j = i - 15360; }
        else if (i < 875520)  { s = s2; j = i - 506880; }
        else if (i < 1121280) { s = s3; j = i - 875520; }
        else                  { s = s4; j = i - 1121280; }
        whd[i] = f2bf(ldf(s, j, f32));
        return;
    }
    i -= 1244160;
    if (i >= 2942) return;
    float v;
    if      (i < 512)  v = ldf(b0, i, f32);
    else if (i < 542)  v = ldf(b1, i - 512, f32);
    else if (i < 1502) v = ldf(b2, i - 542, f32);
    else if (i < 2222) v = ldf(b3, i - 1502, f32);
    else if (i < 2702) v = ldf(b4, i - 2222, f32);
    else               v = ldf(b5, i - 2702, f32);
    bfs[i] = v;
}

// ---------------------------------------------------------------- conv GEMM (R10)
// R9 structure (256x256, BK=64, ring-2, 1 barrier/tile, 32x32x16 MFMA) with a
// CORRECTED LDS swizzle. R9's read map had lanes {l, l+8, l+16, l+24} share a
// bank group (3.25e7 conflicts). New stored map: slot s of row r holds chunk
// 4a+2b+h where (a,h,b) = bits of t = s ^ ((r>>4)&1) ^ (r&7). This makes
// every ds_read_b128's lane->slot map equal C_p ^ (lane>>4) ^ (lane&7),
// C_p in {0,1,4,5} -- the R8-proven conflict-free family (XOR-constant
// shifts preserve bank distinctness). gl2lds writes stay linear (always
// conflict-free); only the per-lane SOURCE column changes (both-sides rule).
__global__ __launch_bounds__(512, 2) void conv_gemm256(
    const u16* __restrict__ xpad, const u16* __restrict__ wt,
    const float* __restrict__ bfs, u16* __restrict__ y)
{
    __shared__ u16 smem[65536];           // 2 bufs x (A 16384 + B 16384) u16
    const int tid = threadIdx.x;

    // bijective XCD remap (m204, nwg=196), pair-major so (n,m0),(n,m1) co-XCD
    const int bx  = blockIdx.x;
    const int xcd = bx & 7, pos = bx >> 3;
    const int L   = (xcd < 4 ? xcd * 25 : 100 + (xcd - 4) * 24) + pos;
    const int m_base = (L & 1) * 256;
    const int n_base = (L >> 1) * 256;

    // staging: lds slot s = tid&7, row r = j*64 + (tid>>3)  (r&31 j-invariant)
    // source chunk: t = s ^ ((r>>4)&1) ^ (r&7); chunk = 4*t[2] + 2*t[0] + t[1]
    const int rq8  = tid >> 3;                                  // 0..63
    const int t_   = (tid & 7) ^ ((tid >> 7) & 1) ^ (rq8 & 7);
    const int chnk = 4 * ((t_ >> 2) & 1) + 2 * (t_ & 1) + ((t_ >> 1) & 1);
    const int sw   = chnk * 8;                                  // src col elems
    const u16* pa = wt + (long)(m_base + rq8) * 512 + sw;       // +j*32768 +aoff

    long sbj[4];
    #pragma unroll
    for (int j = 0; j < 4; ++j) {
        const int n = n_base + j * 64 + rq8;
        int b = n / 12544, r = n % 12544;
        int t = r / 784,   q = r % 784;
        int h = q / 28,    w = q % 28;
        const int sa = ((b * 18 + t) * 30 + h) * 30 + w;
        sbj[j] = (long)sa * 512 + sw;
    }

    // read-side identities (32x32 fragments)
    const int lane = tid & 63, wid = tid >> 6;
    const int l32 = lane & 31, hi = lane >> 5;
    const int wm = wid >> 2;              // 0..1 -> 128 rows
    const int wn = wid & 3;               // 0..3 -> 64 cols
    int rA[4], rB[2];
    #pragma unroll
    for (int mi = 0; mi < 4; ++mi) rA[mi] = (wm * 128 + mi * 32 + l32) * 64;
    #pragma unroll
    for (int ni = 0; ni < 2; ++ni) rB[ni] = 16384 + (wn * 64 + ni * 32 + l32) * 64;
    // k-chunk-pair slots: slot = C_p ^ (lane>>4) ^ (lane&7), C = {0,1,4,5}
    const int xr  = (lane >> 4) ^ (lane & 7);
    const int sk0 = (0 ^ xr) * 8;   // p=0: k  0..15
    const int sk1 = (1 ^ xr) * 8;   // p=1: k 16..31
    const int sk2 = (4 ^ xr) * 8;   // p=2: k 32..47
    const int sk3 = (5 ^ xr) * 8;   // p=3: k 48..63

    f32x16 acc[4][2] = {};

    // prologue: stage tile 0 (tap 0, kc 0)
    {
        u16* dst = smem;
        #pragma unroll
        for (int j = 0; j < 4; ++j)
            gl2lds16(pa + (long)j * 32768, dst + j * 4096 + tid * 8);
        #pragma unroll
        for (int j = 0; j < 4; ++j)
            gl2lds16(xpad + sbj[j], dst + 16384 + j * 4096 + tid * 8);
    }

    for (int kt = 0; kt < 216; ++kt) {
        asm volatile("s_waitcnt vmcnt(0)" ::: "memory");
        asm volatile("s_barrier" ::: "memory");
        const u16* buf = smem + (kt & 1) * 32768;

        // sub0: k-chunk-pairs 0,1
        bf16x8 a0[4], a1[4], b0[2], b1[2];
        #pragma unroll
        for (int mi = 0; mi < 4; ++mi) {
            a0[mi] = *(const bf16x8*)&buf[rA[mi] + sk0];
            a1[mi] = *(const bf16x8*)&buf[rA[mi] + sk1];
        }
        #pragma unroll
        for (int ni = 0; ni < 2; ++ni) {
            b0[ni] = *(const bf16x8*)&buf[rB[ni] + sk0];
            b1[ni] = *(const bf16x8*)&buf[rB[ni] + sk1];
        }

        if (kt < 215) {
            const int kts = kt + 1;
            const int tap = kts >> 3, kc = kts & 7;
            const int kd = tap / 9, r9 = tap - kd * 9;
            const int kh = r9 / 3,  kw = r9 - kh * 3;
            const long aoff = (long)tap * 262144 + kc * 64;
            const long boff = (long)(kd * 900 + kh * 30 + kw) * 512 + kc * 64;
            u16* dst = smem + ((kts & 1) << 15);
            #pragma unroll
            for (int j = 0; j < 4; ++j)
                gl2lds16(pa + aoff + (long)j * 32768, dst + j * 4096 + tid * 8);
            #pragma unroll
            for (int j = 0; j < 4; ++j)
                gl2lds16(xpad + sbj[j] + boff, dst + 16384 + j * 4096 + tid * 8);
        }

        __builtin_amdgcn_s_setprio(1);
        #pragma unroll
        for (int mi = 0; mi < 4; ++mi)
            #pragma unroll
            for (int ni = 0; ni < 2; ++ni)
                acc[mi][ni] = __builtin_amdgcn_mfma_f32_32x32x16_bf16(
                    a0[mi], b0[ni], acc[mi][ni], 0, 0, 0);
        #pragma unroll
        for (int mi = 0; mi < 4; ++mi)
            #pragma unroll
            for (int ni = 0; ni < 2; ++ni)
                acc[mi][ni] = __builtin_amdgcn_mfma_f32_32x32x16_bf16(
                    a1[mi], b1[ni], acc[mi][ni], 0, 0, 0);
        __builtin_amdgcn_s_setprio(0);

        // sub1: k-chunk-pairs 2,3
        bf16x8 a2[4], a3[4], b2[2], b3[2];
        #pragma unroll
        for (int mi = 0; mi < 4; ++mi) {
            a2[mi] = *(const bf16x8*)&buf[rA[mi] + sk2];
            a3[mi] = *(const bf16x8*)&buf[rA[mi] + sk3];
        }
        #pragma unroll
        for (int ni = 0; ni < 2; ++ni) {
            b2[ni] = *(const bf16x8*)&buf[rB[ni] + sk2];
            b3[ni] = *(const bf16x8*)&buf[rB[ni] + sk3];
        }

        __builtin_amdgcn_s_setprio(1);
        #pragma unroll
        for (int mi = 0; mi < 4; ++mi)
            #pragma unroll
            for (int ni = 0; ni < 2; ++ni)
                acc[mi][ni] = __builtin_amdgcn_mfma_f32_32x32x16_bf16(
                    a2[mi], b2[ni], acc[mi][ni], 0, 0, 0);
        #pragma unroll
        for (int mi = 0; mi < 4; ++mi)
            #pragma unroll
            for (int ni = 0; ni < 2; ++ni)
                acc[mi][ni] = __builtin_amdgcn_mfma_f32_32x32x16_bf16(
                    a3[mi], b3[ni], acc[mi][ni], 0, 0, 0);
        __builtin_amdgcn_s_setprio(0);
    }

    // epilogue: bias + relu + bf16 store to y[n][512]
    // C/D: col = l32 (n), row = (reg&3) + 8*(reg>>2) + 4*hi (m within 32)
    #pragma unroll
    for (int mi = 0; mi < 4; ++mi) {
        #pragma unroll
        for (int ni = 0; ni < 2; ++ni) {
            const int ng = n_base + wn * 64 + ni * 32 + l32;
            #pragma unroll
            for (int q = 0; q < 4; ++q) {
                const int mrow = m_base + wm * 128 + mi * 32 + q * 8 + hi * 4;
                float v0 = acc[mi][ni][q * 4 + 0] + bfs[mrow + 0];
                float v1 = acc[mi][ni][q * 4 + 1] + bfs[mrow + 1];
                float v2 = acc[mi][ni][q * 4 + 2] + bfs[mrow + 2];
                float v3 = acc[mi][ni][q * 4 + 3] + bfs[mrow + 3];
                uint2 pv;
                pv.x = (u32)f2bf(fmaxf(v0, 0.f)) | ((u32)f2bf(fmaxf(v1, 0.f)) << 16);
                pv.y = (u32)f2bf(fmaxf(v2, 0.f)) | ((u32)f2bf(fmaxf(v3, 0.f)) << 16);
                *(uint2*)&y[(long)ng * 512 + mrow] = pv;
            }
        }
    }
}

// ---------------------------------------------------------------- fused pools
__device__ __forceinline__ uint2 max4(uint2 A, uint2 Bv)
{
    const u16* a = (const u16*)&A;
    const u16* b = (const u16*)&Bv;
    uint2 R;
    u16* r = (u16*)&R;
    #pragma unroll
    for (int i = 0; i < 4; ++i) r[i] = (bf2f(a[i]) >= bf2f(b[i])) ? a[i] : b[i];
    return R;
}

// One thread owns (b,hw,c4): loads 16 t-slices (uint2 = 4 bf16), computes all
// four temporal pools via a sliding-max tree in registers, writes 13+9+5+1
// outputs. Reads y exactly once (25.7 MB). 200704 threads / 784 blocks.
__global__ void pool_all(const u16* __restrict__ y, u16* __restrict__ p4,
                         u16* __restrict__ p8, u16* __restrict__ p12,
                         u16* __restrict__ p16)
{
    int g = blockIdx.x * 256 + threadIdx.x;
    if (g >= 200704) return;                 // 2*784*128
    const int c4 = g & 127;
    int pos = g >> 7;
    const int hw = pos % 784; const int b = pos / 784;
    const u16* src = y + ((long)(b * 16) * 784 + hw) * 512 + c4 * 4;
    uint2 v[16];
    #pragma unroll
    for (int t = 0; t < 16; ++t)
        v[t] = *(const uint2*)(src + (long)t * 401408);
    uint2 pr[15];
    #pragma unroll
    for (int t = 0; t < 15; ++t) pr[t] = max4(v[t], v[t + 1]);
    uint2 qd[13];
    #pragma unroll
    for (int t = 0; t < 13; ++t) qd[t] = max4(pr[t], pr[t + 2]);
    uint2 e8[9];
    #pragma unroll
    for (int t = 0; t < 9; ++t) e8[t] = max4(qd[t], qd[t + 4]);
    uint2 e12[5];
    #pragma unroll
    for (int t = 0; t < 5; ++t) e12[t] = max4(e8[t], qd[t + 8]);
    uint2 e16 = max4(e8[0], e8[8]);

    const long col = (long)hw * 512 + c4 * 4;
    #pragma unroll
    for (int t = 0; t < 13; ++t)
        *(uint2*)&p4[((long)(b * 13 + t) * 784) * 512 + col] = qd[t];
    #pragma unroll
    for (int t = 0; t < 9; ++t)
        *(uint2*)&p8[((long)(b * 9 + t) * 784) * 512 + col] = e8[t];
    #pragma unroll
    for (int t = 0; t < 5; ++t)
        *(uint2*)&p12[((long)(b * 5 + t) * 784) * 512 + col] = e12[t];
    *(uint2*)&p16[((long)b * 784) * 512 + col] = e16;
}

// ---------------------------------------------------------------- fused heads GEMM
// BK=64 (8 K-steps), XOR-swizzled LDS staging. (R2-proven version.)
__global__ __launch_bounds__(256, 2) void heads_gemm(
    const u16* __restrict__ p16, const u16* __restrict__ p12,
    const u16* __restrict__ p8,  const u16* __restrict__ p4,
    const u16* __restrict__ wcls, const u16* __restrict__ wb1,
    const u16* __restrict__ wb34, const u16* __restrict__ wb2,
    const u16* __restrict__ wb4,  const float* __restrict__ bfs,
    float* __restrict__ clsr, void* __restrict__ outv,
    const u32* __restrict__ im)
{
    const int f32 = is_f32(im);
    int bid = blockIdx.x;
    const u16* pool; const u16* wbp; int Ti, CH, nt, mt; long boff, coff, ooff;
    if (bid < 104)      {             nt = bid % 13;  mt = bid / 13;  pool = p16; wbp = wb1;  Ti = 1;  CH = 960; boff = 542;  coff = 0;      ooff = 1317120; }
    else if (bid < 476) { bid -= 104; nt = bid % 62;  mt = bid / 62;  pool = p12; wbp = wb34; Ti = 5;  CH = 720; boff = 1502; coff = 47040;  ooff = 2822400; }
    else if (bid < 920) { bid -= 476; nt = bid % 111; mt = bid / 111; pool = p8;  wbp = wb2;  Ti = 9;  CH = 480; boff = 2222; coff = 282240; ooff = 8467200; }
    else                { bid -= 920; nt = bid % 160; mt = bid / 160; pool = p4;  wbp = wb4;  Ti = 13; CH = 240; boff = 2702; coff = 705600; ooff = 15240960; }
    const int M = 30 + CH;
    const int THW = Ti * 784;
    const int N = 2 * THW;
    const int n_base = nt * 128;
    const int m_base = mt * 128;

    __shared__ u16 lds_a[128 * 64];
    __shared__ u16 lds_b[128 * 64];
    const int tid = threadIdx.x;
    const int lane = tid & 63;
    const int wid  = tid >> 6;
    const int quad = lane >> 4;
    const int l16  = lane & 15;
    const int wm = (wid & 1) * 64;
    const int wn = (wid >> 1) * 64;
    const int srow = tid >> 3;
    const int lc8  = ((tid & 7) ^ (srow & 7)) * 8;

    const u16* arow[4]; const u16* brow[4];
    #pragma unroll
    for (int j = 0; j < 4; ++j) {
        int m = m_base + j * 32 + srow; if (m > M - 1) m = M - 1;
        arow[j] = ((m < 30) ? (wcls + m * 512) : (wbp + (m - 30) * 512)) + lc8;
        int n = n_base + j * 32 + srow; if (n > N - 1) n = N - 1;
        brow[j] = pool + (long)n * 512 + lc8;
    }

    u16* ldst_a = &lds_a[tid * 8];
    u16* ldst_b = &lds_b[tid * 8];

    int rowA[4], rowB[4];
    #pragma unroll
    for (int i = 0; i < 4; ++i) {
        rowA[i] = (wm + i * 16 + l16) * 64;
        rowB[i] = (wn + i * 16 + l16) * 64;
    }
    const int cx  = l16 & 7;
    const int ch0 = (quad ^ cx) * 8;
    const int ch1 = ((4 + quad) ^ cx) * 8;

    f32x4 acc[4][4] = {};
    for (int kc = 0; kc < 8; ++kc) {
        const int kcol = kc * 64;
        #pragma unroll
        for (int j = 0; j < 4; ++j)
            gl2lds16(arow[j] + kcol, ldst_a + j * 2048);
        #pragma unroll
        for (int j = 0; j < 4; ++j)
            gl2lds16(brow[j] + kcol, ldst_b + j * 2048);
        __syncthreads();
        #pragma unroll
        for (int h = 0; h < 2; ++h) {
            const int co = h ? ch1 : ch0;
            bf16x8 af[4], bfr[4];
            #pragma unroll
            for (int mi = 0; mi < 4; ++mi)
                af[mi]  = *(const bf16x8*)&lds_a[rowA[mi] + co];
            #pragma unroll
            for (int ni = 0; ni < 4; ++ni)
                bfr[ni] = *(const bf16x8*)&lds_b[rowB[ni] + co];
            #pragma unroll
            for (int mi = 0; mi < 4; ++mi)
                #pragma unroll
                for (int ni = 0; ni < 4; ++ni)
                    acc[mi][ni] = __builtin_amdgcn_mfma_f32_16x16x32_bf16(
                        af[mi], bfr[ni], acc[mi][ni], 0, 0, 0);
        }
        __syncthreads();
    }
    const float* bcls = bfs + 512;
    const float* bb   = bfs + boff;
    #pragma unroll
    for (int mi = 0; mi < 4; ++mi) {
        const int mrow = m_base + wm + mi * 16 + quad * 4;
        #pragma unroll
        for (int ni = 0; ni < 4; ++ni) {
            const int ng = n_base + wn + ni * 16 + l16;
            if (ng >= N) continue;
            const int b  = ng / THW;
            const int rr = ng % THW;
            f32x4 a = acc[mi][ni];
            #pragma unroll
            for (int r = 0; r < 4; ++r) {
                const int m = mrow + r;
                if (m >= M) break;
                const float bias = (m < 30) ? bcls[m] : bb[m - 30];
                const float v = a[r] + bias;
                if (m < 30) {
                    clsr[coff + ((long)(b * 30 + m)) * THW + rr] = v;
                } else {
                    const long oi = ooff + ((long)(b * CH + (m - 30))) * THW + rr;
                    if (f32) ((float*)outv)[oi] = v;
                    else     ((u16*)outv)[oi]   = f2bf(v);
                }
            }
        }
    }
}

// ---------------------------------------------------------------- pair softmax
__global__ void softmax_all(const float* __restrict__ clsr,
                            void* __restrict__ outv, const u32* __restrict__ im)
{
    const int f32 = is_f32(im);
    int g = blockIdx.x * 256 + threadIdx.x;
    if (g >= 658560) return;
    int Ti; long off;
    if      (g < 23520)  { Ti = 1;  off = 0; }
    else if (g < 141120) { Ti = 5;  off = 47040;  g -= 23520; }
    else if (g < 352800) { Ti = 9;  off = 282240; g -= 141120; }
    else                 { Ti = 13; off = 705600; g -= 352800; }
    const int THW = Ti * 784;
    const int rr = g % THW;
    int r2 = g / THW;
    const int j = r2 % 15; const int b = r2 / 15;
    const long i0 = off + ((long)(b * 30 + j)) * THW + rr;
    const long i1 = off + ((long)(b * 30 + j + 15)) * THW + rr;
    const float s0 = clsr[i0], s1 = clsr[i1];
    const float mx = fmaxf(s0, s1);
    const float e0 = __expf(s0 - mx), e1 = __expf(s1 - mx);
    const float inv = 1.0f / (e0 + e1);
    if (f32) {
        ((float*)outv)[i0] = e0 * inv;
        ((float*)outv)[i1] = e1 * inv;
    } else {
        ((u16*)outv)[i0] = f2bf(e0 * inv);
        ((u16*)outv)[i1] = f2bf(e1 * inv);
    }
}

// ---------------------------------------------------------------- launcher
extern "C" void kernel_launch(void* const* d_in, const int* in_sizes, int n_in,
                              void* d_out, int out_size, void* d_ws, size_t ws_size,
                              hipStream_t stream)
{
    const void* base_feat = d_in[0];
    const u32*  im_info   = (const u32*)d_in[1];
    const void* W_conv    = d_in[4];
    const void* b_conv    = d_in[5];
    const void* W_cls     = d_in[6];
    const void* b_cls     = d_in[7];
    const void* W_bbox    = d_in[8];
    const void* b_bbox    = d_in[9];
    const void* W_bbox34  = d_in[10];
    const void* b_bbox34  = d_in[11];
    const void* W_bbox2   = d_in[12];
    const void* b_bbox2   = d_in[13];
    const void* W_bbox4   = d_in[14];
    const void* b_bbox4   = d_in[15];

    char* ws = (char*)d_ws;
    u16*   xpad = (u16*)  (ws + 0);           // 33,177,600
    u16*   wt   = (u16*)  (ws + 33177600);    // 14,155,776 -> 47,333,376
    u16*   y    = (u16*)  (ws + 47333376);    // 25,690,112 -> 73,023,488
    u16*   p4   = (u16*)  (ws + 73023488);    // 20,873,216 -> 93,896,704
    u16*   p8   = (u16*)  (ws + 93896704);    // 14,450,688 -> 108,347,392
    u16*   p12  = (u16*)  (ws + 108347392);   //  8,028,160 -> 116,375,552
    u16*   p16  = (u16*)  (ws + 116375552);   //  1,605,632 -> 117,981,184
    float* clsr = (float*)(ws + 117981184);   //  5,268,480 -> 123,249,664
    u16*   whd  = (u16*)  (ws + 123249728);   //  2,488,320 -> 125,738,048
    float* bfs  = (float*)(ws + 125738048);   //     11,768

    u16* w_cls_b  = whd;
    u16* w_b1_b   = whd + 15360;
    u16* w_b34_b  = whd + 506880;
    u16* w_b2_b   = whd + 875520;
    u16* w_b4_b   = whd + 1121280;

    zero_halo<<<1828, 256, 0, stream>>>(xpad);
    pad_fill<<<7168, 256, 0, stream>>>(base_feat, xpad, im_info);
    wt_transform<<<1024, 256, 0, stream>>>(W_conv, wt, im_info);
    cvt_all<<<4873, 256, 0, stream>>>(W_cls, W_bbox, W_bbox34, W_bbox2, W_bbox4,
                                      b_conv, b_cls, b_bbox, b_bbox34, b_bbox2,
                                      b_bbox4, whd, bfs, im_info);

    conv_gemm256<<<196, 512, 0, stream>>>(xpad, wt, bfs, y);

    pool_all<<<784, 256, 0, stream>>>(y, p4, p8, p12, p16);

    heads_gemm<<<1400, 256, 0, stream>>>(p16, p12, p8, p4,
                                         w_cls_b, w_b1_b, w_b34_b, w_b2_b, w_b4_b,
                                         bfs, clsr, d_out, im_info);

    softmax_all<<<2573, 256, 0, stream>>>(clsr, d_out, im_info);
}

// Round 8
// 569.358 us; speedup vs baseline: 1.2492x; 1.2492x over previous
//
#include <hip/hip_runtime.h>

typedef unsigned short u16;
typedef unsigned int   u32;
typedef __bf16  bf16x8 __attribute__((ext_vector_type(8)));
typedef float   f32x4  __attribute__((ext_vector_type(4)));

__device__ __forceinline__ float bf2f(u16 u) {
    u32 v = ((u32)u) << 16;
    return __builtin_bit_cast(float, v);
}
__device__ __forceinline__ u16 f2bf(float f) {
    u32 u = __builtin_bit_cast(u32, f);
    return (u16)((u + 0x7FFFu + ((u >> 16) & 1u)) >> 16);   // RNE
}
__device__ __forceinline__ float ldf(const void* p, long i, int f32) {
    return f32 ? ((const float*)p)[i] : bf2f(((const u16*)p)[i]);
}
__device__ __forceinline__ int is_f32(const u32* im) {
    return im[0] == 0x43E00000u;   // 448.0f fp32 vs packed bf16 (0x43E043E0)
}
// async global->LDS, 16B per lane (LDS dst = wave-uniform base + lane*16)
__device__ __forceinline__ void gl2lds16(const u16* g, u16* l) {
    __builtin_amdgcn_global_load_lds(
        (const __attribute__((address_space(1))) void*)g,
        (__attribute__((address_space(3))) void*)l, 16, 0, 0);
}

// ------------------------------------------- zero only the pad halo of xpad
__global__ void zero_halo(u16* __restrict__ xpad)
{
    int i = blockIdx.x * 256 + threadIdx.x;
    if (i < 230400) {                       // t in {0,17}: 2b*2t*900*64
        int c8 = i & 63; int pos = i >> 6;
        int p = pos % 900; pos /= 900;
        int t = (pos & 1) * 17; int b = pos >> 1;
        long o = (((long)(b * 18 + t) * 900) + p) * 512 + c8 * 8;
        *(uint4*)&xpad[o] = uint4{0u, 0u, 0u, 0u};
        return;
    }
    i -= 230400;
    if (i < 122880) {                       // t 1..16, h in {0,29}: 2*16*2*30*64
        int c8 = i & 63; int pos = i >> 6;
        int w = pos % 30; pos /= 30;
        int h = (pos & 1) * 29; pos >>= 1;
        int t = pos % 16 + 1; int b = pos / 16;
        long o = ((((long)(b * 18 + t) * 30 + h) * 30) + w) * 512 + c8 * 8;
        *(uint4*)&xpad[o] = uint4{0u, 0u, 0u, 0u};
        return;
    }
    i -= 122880;
    if (i < 114688) {                       // t 1..16, h 1..28, w in {0,29}
        int c8 = i & 63; int pos = i >> 6;
        int w = (pos & 1) * 29; pos >>= 1;
        int h = pos % 28 + 1; pos /= 28;
        int t = pos % 16 + 1; int b = pos / 16;
        long o = ((((long)(b * 18 + t) * 30 + h) * 30) + w) * 512 + c8 * 8;
        *(uint4*)&xpad[o] = uint4{0u, 0u, 0u, 0u};
    }
}

// ------------------------------------------------- pad+transpose base_feat
__global__ void pad_fill(const void* __restrict__ src, u16* __restrict__ xpad,
                         const u32* __restrict__ im)
{
    const int f32 = is_f32(im);
    __shared__ u16 lds[56 * 40];
    int blk = blockIdx.x;
    const int h2  = blk % 14;  blk /= 14;
    const int c32 = blk & 15;  blk >>= 4;
    const int t   = blk & 15;
    const int b   = blk >> 4;
    const int tid = threadIdx.x;
    const long sbase = ((long)(b * 512 + c32 * 32) * 16 + t) * 784 + h2 * 56;
    #pragma unroll
    for (int it = tid; it < 1792; it += 256) {
        const int c = it / 56, p = it - c * 56;
        float v = f32 ? ((const float*)src)[sbase + (long)c * 12544 + p]
                      : bf2f(((const u16*)src)[sbase + (long)c * 12544 + p]);
        lds[p * 40 + c] = f2bf(v);
    }
    __syncthreads();
    if (tid < 224) {
        const int p = tid >> 2, g = tid & 3;
        const int h = h2 * 2 + p / 28, w = p % 28;
        const long o = (((long)(b * 18 + t + 1) * 30 + h + 1) * 30 + (w + 1)) * 512
                       + c32 * 32 + g * 8;
        *(uint4*)&xpad[o] = *(const uint4*)&lds[p * 40 + g * 8];
    }
}

// ------------------------------------------------- W_conv [O][I][27] -> Wt[27][O][I]
__global__ void wt_transform(const void* __restrict__ wconv, u16* __restrict__ wt,
                             const u32* __restrict__ im)
{
    const int f32 = is_f32(im);
    __shared__ u16 lds[256 * 28];
    const int tid = threadIdx.x;
    const int pair_base = blockIdx.x * 256;
    const long s0 = (long)pair_base * 27;
    for (int it = tid; it < 256 * 27; it += 256) {
        const int p = it / 27, o = it - p * 27;
        float v = f32 ? ((const float*)wconv)[s0 + it]
                      : bf2f(((const u16*)wconv)[s0 + it]);
        lds[p * 28 + o] = f2bf(v);
    }
    __syncthreads();
    #pragma unroll
    for (int off = 0; off < 27; ++off)
        wt[(long)off * 262144 + pair_base + tid] = lds[tid * 28 + off];
}

// ------------------------------------------------- head weights + biases (merged)
__global__ void cvt_all(const void* s0, const void* s1, const void* s2,
                        const void* s3, const void* s4,
                        const void* b0, const void* b1, const void* b2,
                        const void* b3, const void* b4, const void* b5,
                        u16* __restrict__ whd, float* __restrict__ bfs,
                        const u32* __restrict__ im)
{
    const int f32 = is_f32(im);
    int i = blockIdx.x * 256 + threadIdx.x;
    if (i < 1244160) {
        const void* s; long j;
        if      (i < 15360)   { s = s0; j = i; }
        else if (i < 506880)  { s = s1; j = i - 15360; }
        else if (i < 875520)  { s = s2; j = i - 506880; }
        else if (i < 1121280) { s = s3; j = i - 875520; }
        else                  { s = s4; j = i - 1121280; }
        whd[i] = f2bf(ldf(s, j, f32));
        return;
    }
    i -= 1244160;
    if (i >= 2942) return;
    float v;
    if      (i < 512)  v = ldf(b0, i, f32);
    else if (i < 542)  v = ldf(b1, i - 512, f32);
    else if (i < 1502) v = ldf(b2, i - 542, f32);
    else if (i < 2222) v = ldf(b3, i - 1502, f32);
    else if (i < 2702) v = ldf(b4, i - 2222, f32);
    else               v = ldf(b5, i - 2702, f32);
    bfs[i] = v;
}

// ---------------------------------------------------------------- conv GEMM (R8, proven 341us)
// 256x256 tile, BK=64, ring-2 LDS (2 x 64 KB), ONE barrier + ONE vmcnt(0)
// per 64-K tile (216 total): vmcnt(0) [stage(kt) issued ~2400cy ago -> ~free];
// s_barrier ; 12 ds_read (sub0) ; 8 gl2lds stage(kt+1) ; 32 MFMA ;
// 12 ds_read (sub1) ; 32 MFMA.  16x16x32 MFMA (32x32x16 regressed twice:
// R9 bank conflicts, R10 FETCH+30% -- see journal).
// LDS: A[256][64]+B[256][64] bf16, 8-slot XOR swizzle (slot ^ (row&7));
// gl2lds source carries the inverse (both-sides rule). Measured: 0 conflicts.
__global__ __launch_bounds__(512, 2) void conv_gemm256(
    const u16* __restrict__ xpad, const u16* __restrict__ wt,
    const float* __restrict__ bfs, u16* __restrict__ y)
{
    __shared__ u16 smem[65536];           // 2 bufs x (A 16384 + B 16384) u16
    const int tid = threadIdx.x;

    // bijective XCD remap (m204, nwg=196), pair-major so (n,m0),(n,m1) co-XCD
    const int bx  = blockIdx.x;
    const int xcd = bx & 7, pos = bx >> 3;
    const int L   = (xcd < 4 ? xcd * 25 : 100 + (xcd - 4) * 24) + pos;
    const int m_base = (L & 1) * 256;
    const int n_base = (L >> 1) * 256;

    // staging: granule g = j*512 + tid; row = g>>3; lds slot = tid&7;
    // source slot = (tid&7) ^ (row&7)  (j-independent)
    const int rq8 = tid >> 3;                                   // 0..63
    const int sw  = (((tid & 7) ^ (rq8 & 7))) * 8;              // src col elems
    const u16* pa = wt + (long)(m_base + rq8) * 512 + sw;       // +j*32768 +aoff

    long sbj[4];
    #pragma unroll
    for (int j = 0; j < 4; ++j) {
        const int n = n_base + j * 64 + rq8;
        int b = n / 12544, r = n % 12544;
        int t = r / 784,   q = r % 784;
        int h = q / 28,    w = q % 28;
        const int sa = ((b * 18 + t) * 30 + h) * 30 + w;
        sbj[j] = (long)sa * 512 + sw;
    }

    // read-side identities
    const int lane = tid & 63, wid = tid >> 6;
    const int l16 = lane & 15, quad = lane >> 4;
    const int wm = wid >> 2;              // 0..1 -> 128 rows
    const int wn = wid & 3;               // 0..3 -> 64 cols
    const int x7 = l16 & 7;
    const int o0 = (quad ^ x7) * 8;             // sub0 k-slot (k 0..31)
    const int o1 = ((4 + quad) ^ x7) * 8;       // sub1 k-slot (k 32..63)
    int rowA[8], rowB[4];
    #pragma unroll
    for (int mi = 0; mi < 8; ++mi) rowA[mi] = (wm * 128 + mi * 16 + l16) * 64;
    #pragma unroll
    for (int ni = 0; ni < 4; ++ni) rowB[ni] = 16384 + (wn * 64 + ni * 16 + l16) * 64;

    f32x4 acc[8][4] = {};

    // prologue: stage tile 0 (tap 0, kc 0)
    {
        u16* dst = smem;
        #pragma unroll
        for (int j = 0; j < 4; ++j)
            gl2lds16(pa + (long)j * 32768, dst + j * 4096 + tid * 8);
        #pragma unroll
        for (int j = 0; j < 4; ++j)
            gl2lds16(xpad + sbj[j], dst + 16384 + j * 4096 + tid * 8);
    }

    for (int kt = 0; kt < 216; ++kt) {
        asm volatile("s_waitcnt vmcnt(0)" ::: "memory");
        asm volatile("s_barrier" ::: "memory");
        const u16* buf = smem + (kt & 1) * 32768;

        bf16x8 af[8], bfr[4];
        #pragma unroll
        for (int mi = 0; mi < 4; ++mi)
            af[mi] = *(const bf16x8*)&buf[rowA[mi] + o0];
        #pragma unroll
        for (int ni = 0; ni < 4; ++ni)
            bfr[ni] = *(const bf16x8*)&buf[rowB[ni] + o0];
        #pragma unroll
        for (int mi = 4; mi < 8; ++mi)
            af[mi] = *(const bf16x8*)&buf[rowA[mi] + o0];

        if (kt < 215) {
            const int kts = kt + 1;
            const int tap = kts >> 3, kc = kts & 7;
            const int kd = tap / 9, r9 = tap - kd * 9;
            const int kh = r9 / 3,  kw = r9 - kh * 3;
            const long aoff = (long)tap * 262144 + kc * 64;
            const long boff = (long)(kd * 900 + kh * 30 + kw) * 512 + kc * 64;
            u16* dst = smem + ((kts & 1) << 15);
            #pragma unroll
            for (int j = 0; j < 4; ++j)
                gl2lds16(pa + aoff + (long)j * 32768, dst + j * 4096 + tid * 8);
            #pragma unroll
            for (int j = 0; j < 4; ++j)
                gl2lds16(xpad + sbj[j] + boff, dst + 16384 + j * 4096 + tid * 8);
        }

        __builtin_amdgcn_s_setprio(1);
        #pragma unroll
        for (int mi = 0; mi < 8; ++mi)
            #pragma unroll
            for (int ni = 0; ni < 4; ++ni)
                acc[mi][ni] = __builtin_amdgcn_mfma_f32_16x16x32_bf16(
                    af[mi], bfr[ni], acc[mi][ni], 0, 0, 0);
        __builtin_amdgcn_s_setprio(0);

        bf16x8 ag[8], bgr[4];
        #pragma unroll
        for (int mi = 0; mi < 8; ++mi)
            ag[mi] = *(const bf16x8*)&buf[rowA[mi] + o1];
        #pragma unroll
        for (int ni = 0; ni < 4; ++ni)
            bgr[ni] = *(const bf16x8*)&buf[rowB[ni] + o1];

        __builtin_amdgcn_s_setprio(1);
        #pragma unroll
        for (int mi = 0; mi < 8; ++mi)
            #pragma unroll
            for (int ni = 0; ni < 4; ++ni)
                acc[mi][ni] = __builtin_amdgcn_mfma_f32_16x16x32_bf16(
                    ag[mi], bgr[ni], acc[mi][ni], 0, 0, 0);
        __builtin_amdgcn_s_setprio(0);
    }

    // epilogue: bias + relu + bf16 store to y[n][512]
    #pragma unroll
    for (int mi = 0; mi < 8; ++mi) {
        const int mrow = m_base + wm * 128 + mi * 16 + quad * 4;
        float bias[4];
        #pragma unroll
        for (int r = 0; r < 4; ++r) bias[r] = bfs[mrow + r];
        #pragma unroll
        for (int ni = 0; ni < 4; ++ni) {
            const int ng = n_base + wn * 64 + ni * 16 + l16;
            f32x4 a = acc[mi][ni];
            u16 o0v = f2bf(fmaxf(a[0] + bias[0], 0.f));
            u16 o1v = f2bf(fmaxf(a[1] + bias[1], 0.f));
            u16 o2v = f2bf(fmaxf(a[2] + bias[2], 0.f));
            u16 o3v = f2bf(fmaxf(a[3] + bias[3], 0.f));
            uint2 pv;
            pv.x = (u32)o0v | ((u32)o1v << 16);
            pv.y = (u32)o2v | ((u32)o3v << 16);
            *(uint2*)&y[(long)ng * 512 + mrow] = pv;
        }
    }
}

// ---------------------------------------------------------------- fused pools
__device__ __forceinline__ uint2 max4(uint2 A, uint2 Bv)
{
    const u16* a = (const u16*)&A;
    const u16* b = (const u16*)&Bv;
    uint2 R;
    u16* r = (u16*)&R;
    #pragma unroll
    for (int i = 0; i < 4; ++i) r[i] = (bf2f(a[i]) >= bf2f(b[i])) ? a[i] : b[i];
    return R;
}

// One thread owns (b,hw,c4): loads 16 t-slices (uint2 = 4 bf16), computes all
// four temporal pools via a sliding-max tree in registers, writes 13+9+5+1
// outputs. Reads y exactly once (25.7 MB). 200704 threads / 784 blocks.
__global__ void pool_all(const u16* __restrict__ y, u16* __restrict__ p4,
                         u16* __restrict__ p8, u16* __restrict__ p12,
                         u16* __restrict__ p16)
{
    int g = blockIdx.x * 256 + threadIdx.x;
    if (g >= 200704) return;                 // 2*784*128
    const int c4 = g & 127;
    int pos = g >> 7;
    const int hw = pos % 784; const int b = pos / 784;
    const u16* src = y + ((long)(b * 16) * 784 + hw) * 512 + c4 * 4;
    uint2 v[16];
    #pragma unroll
    for (int t = 0; t < 16; ++t)
        v[t] = *(const uint2*)(src + (long)t * 401408);
    uint2 pr[15];
    #pragma unroll
    for (int t = 0; t < 15; ++t) pr[t] = max4(v[t], v[t + 1]);
    uint2 qd[13];
    #pragma unroll
    for (int t = 0; t < 13; ++t) qd[t] = max4(pr[t], pr[t + 2]);
    uint2 e8[9];
    #pragma unroll
    for (int t = 0; t < 9; ++t) e8[t] = max4(qd[t], qd[t + 4]);
    uint2 e12[5];
    #pragma unroll
    for (int t = 0; t < 5; ++t) e12[t] = max4(e8[t], qd[t + 8]);
    uint2 e16 = max4(e8[0], e8[8]);

    const long col = (long)hw * 512 + c4 * 4;
    #pragma unroll
    for (int t = 0; t < 13; ++t)
        *(uint2*)&p4[((long)(b * 13 + t) * 784) * 512 + col] = qd[t];
    #pragma unroll
    for (int t = 0; t < 9; ++t)
        *(uint2*)&p8[((long)(b * 9 + t) * 784) * 512 + col] = e8[t];
    #pragma unroll
    for (int t = 0; t < 5; ++t)
        *(uint2*)&p12[((long)(b * 5 + t) * 784) * 512 + col] = e12[t];
    *(uint2*)&p16[((long)b * 784) * 512 + col] = e16;
}

// ---------------------------------------------------------------- fused heads GEMM
// R11: ring-2 of BK=32 within the SAME 32 KB LDS as the R2-proven body
// (occupancy unchanged), conv-R6 schedule: per step {vmcnt(0) on loads issued
// one step earlier; one s_barrier; 8 ds_read_b128; stage next 16 KB; setprio
// 16 MFMA}. 16 steps. LDS map = original conv's measured-0-conflict family:
// stored slot s ^ ((row>>1)&3) on 64B rows; src chunk (tid&3)^((tid>>3)&3);
// read slot quad ^ ((l16>>1)&3).
__global__ __launch_bounds__(256, 2) void heads_gemm(
    const u16* __restrict__ p16, const u16* __restrict__ p12,
    const u16* __restrict__ p8,  const u16* __restrict__ p4,
    const u16* __restrict__ wcls, const u16* __restrict__ wb1,
    const u16* __restrict__ wb34, const u16* __restrict__ wb2,
    const u16* __restrict__ wb4,  const float* __restrict__ bfs,
    float* __restrict__ clsr, void* __restrict__ outv,
    const u32* __restrict__ im)
{
    const int f32 = is_f32(im);
    int bid = blockIdx.x;
    const u16* pool; const u16* wbp; int Ti, CH, nt, mt; long boff, coff, ooff;
    if (bid < 104)      {             nt = bid % 13;  mt = bid / 13;  pool = p16; wbp = wb1;  Ti = 1;  CH = 960; boff = 542;  coff = 0;      ooff = 1317120; }
    else if (bid < 476) { bid -= 104; nt = bid % 62;  mt = bid / 62;  pool = p12; wbp = wb34; Ti = 5;  CH = 720; boff = 1502; coff = 47040;  ooff = 2822400; }
    else if (bid < 920) { bid -= 476; nt = bid % 111; mt = bid / 111; pool = p8;  wbp = wb2;  Ti = 9;  CH = 480; boff = 2222; coff = 282240; ooff = 8467200; }
    else                { bid -= 920; nt = bid % 160; mt = bid / 160; pool = p4;  wbp = wb4;  Ti = 13; CH = 240; boff = 2702; coff = 705600; ooff = 15240960; }
    const int M = 30 + CH;
    const int THW = Ti * 784;
    const int N = 2 * THW;
    const int n_base = nt * 128;
    const int m_base = mt * 128;

    __shared__ u16 lds[16384];               // 2 bufs x (A 4096 + B 4096) u16
    const int tid = threadIdx.x;
    const int lane = tid & 63;
    const int wid  = tid >> 6;
    const int quad = lane >> 4;
    const int l16  = lane & 15;
    const int wm = (wid & 1) * 64;
    const int wn = (wid >> 1) * 64;

    // staging: granule g = i*256 + tid (i=0,1); row = i*64 + (tid>>2);
    // src chunk kk = ((tid&3) ^ ((tid>>3)&3)) * 8   (g>>3 == tid>>3 mod 4)
    const int srow = tid >> 2;            // 0..63, + i*64
    const int kk   = (((tid & 3) ^ ((tid >> 3) & 3))) * 8;

    const u16* arow[2]; const u16* brow[2];
    #pragma unroll
    for (int i = 0; i < 2; ++i) {
        int m = m_base + i * 64 + srow; if (m > M - 1) m = M - 1;
        arow[i] = ((m < 30) ? (wcls + m * 512) : (wbp + (m - 30) * 512)) + kk;
        int n = n_base + i * 64 + srow; if (n > N - 1) n = N - 1;
        brow[i] = pool + (long)n * 512 + kk;
    }

    // read offsets: row*32 elems + swizzled 16B slot
    const int co = (quad ^ ((l16 >> 1) & 3)) * 8;
    int rowA[4], rowB[4];
    #pragma unroll
    for (int i = 0; i < 4; ++i) {
        rowA[i] = (wm + i * 16 + l16) * 32 + co;
        rowB[i] = 4096 + (wn + i * 16 + l16) * 32 + co;
    }

    // prologue: stage kc=0 into buf 0
    #pragma unroll
    for (int i = 0; i < 2; ++i)
        gl2lds16(arow[i], &lds[i * 2048 + tid * 8]);
    #pragma unroll
    for (int i = 0; i < 2; ++i)
        gl2lds16(brow[i], &lds[4096 + i * 2048 + tid * 8]);

    f32x4 acc[4][4] = {};
    for (int kc = 0; kc < 16; ++kc) {
        asm volatile("s_waitcnt vmcnt(0)" ::: "memory");
        asm volatile("s_barrier" ::: "memory");
        const u16* buf = lds + (kc & 1) * 8192;
        bf16x8 af[4], bfr[4];
        #pragma unroll
        for (int mi = 0; mi < 4; ++mi)
            af[mi]  = *(const bf16x8*)&buf[rowA[mi]];
        #pragma unroll
        for (int ni = 0; ni < 4; ++ni)
            bfr[ni] = *(const bf16x8*)&buf[rowB[ni]];
        if (kc < 15) {
            const int kcol = (kc + 1) * 32;
            u16* dst = lds + ((kc + 1) & 1) * 8192 + tid * 8;
            #pragma unroll
            for (int i = 0; i < 2; ++i)
                gl2lds16(arow[i] + kcol, dst + i * 2048);
            #pragma unroll
            for (int i = 0; i < 2; ++i)
                gl2lds16(brow[i] + kcol, dst + 4096 + i * 2048);
        }
        __builtin_amdgcn_s_setprio(1);
        #pragma unroll
        for (int mi = 0; mi < 4; ++mi)
            #pragma unroll
            for (int ni = 0; ni < 4; ++ni)
                acc[mi][ni] = __builtin_amdgcn_mfma_f32_16x16x32_bf16(
                    af[mi], bfr[ni], acc[mi][ni], 0, 0, 0);
        __builtin_amdgcn_s_setprio(0);
    }

    const float* bcls = bfs + 512;
    const float* bb   = bfs + boff;
    #pragma unroll
    for (int mi = 0; mi < 4; ++mi) {
        const int mrow = m_base + wm + mi * 16 + quad * 4;
        #pragma unroll
        for (int ni = 0; ni < 4; ++ni) {
            const int ng = n_base + wn + ni * 16 + l16;
            if (ng >= N) continue;
            const int b  = ng / THW;
            const int rr = ng % THW;
            f32x4 a = acc[mi][ni];
            #pragma unroll
            for (int r = 0; r < 4; ++r) {
                const int m = mrow + r;
                if (m >= M) break;
                const float bias = (m < 30) ? bcls[m] : bb[m - 30];
                const float v = a[r] + bias;
                if (m < 30) {
                    clsr[coff + ((long)(b * 30 + m)) * THW + rr] = v;
                } else {
                    const long oi = ooff + ((long)(b * CH + (m - 30))) * THW + rr;
                    if (f32) ((float*)outv)[oi] = v;
                    else     ((u16*)outv)[oi]   = f2bf(v);
                }
            }
        }
    }
}

// ---------------------------------------------------------------- pair softmax
__global__ void softmax_all(const float* __restrict__ clsr,
                            void* __restrict__ outv, const u32* __restrict__ im)
{
    const int f32 = is_f32(im);
    int g = blockIdx.x * 256 + threadIdx.x;
    if (g >= 658560) return;
    int Ti; long off;
    if      (g < 23520)  { Ti = 1;  off = 0; }
    else if (g < 141120) { Ti = 5;  off = 47040;  g -= 23520; }
    else if (g < 352800) { Ti = 9;  off = 282240; g -= 141120; }
    else                 { Ti = 13; off = 705600; g -= 352800; }
    const int THW = Ti * 784;
    const int rr = g % THW;
    int r2 = g / THW;
    const int j = r2 % 15; const int b = r2 / 15;
    const long i0 = off + ((long)(b * 30 + j)) * THW + rr;
    const long i1 = off + ((long)(b * 30 + j + 15)) * THW + rr;
    const float s0 = clsr[i0], s1 = clsr[i1];
    const float mx = fmaxf(s0, s1);
    const float e0 = __expf(s0 - mx), e1 = __expf(s1 - mx);
    const float inv = 1.0f / (e0 + e1);
    if (f32) {
        ((float*)outv)[i0] = e0 * inv;
        ((float*)outv)[i1] = e1 * inv;
    } else {
        ((u16*)outv)[i0] = f2bf(e0 * inv);
        ((u16*)outv)[i1] = f2bf(e1 * inv);
    }
}

// ---------------------------------------------------------------- launcher
extern "C" void kernel_launch(void* const* d_in, const int* in_sizes, int n_in,
                              void* d_out, int out_size, void* d_ws, size_t ws_size,
                              hipStream_t stream)
{
    const void* base_feat = d_in[0];
    const u32*  im_info   = (const u32*)d_in[1];
    const void* W_conv    = d_in[4];
    const void* b_conv    = d_in[5];
    const void* W_cls     = d_in[6];
    const void* b_cls     = d_in[7];
    const void* W_bbox    = d_in[8];
    const void* b_bbox    = d_in[9];
    const void* W_bbox34  = d_in[10];
    const void* b_bbox34  = d_in[11];
    const void* W_bbox2   = d_in[12];
    const void* b_bbox2   = d_in[13];
    const void* W_bbox4   = d_in[14];
    const void* b_bbox4   = d_in[15];

    char* ws = (char*)d_ws;
    u16*   xpad = (u16*)  (ws + 0);           // 33,177,600
    u16*   wt   = (u16*)  (ws + 33177600);    // 14,155,776 -> 47,333,376
    u16*   y    = (u16*)  (ws + 47333376);    // 25,690,112 -> 73,023,488
    u16*   p4   = (u16*)  (ws + 73023488);    // 20,873,216 -> 93,896,704
    u16*   p8   = (u16*)  (ws + 93896704);    // 14,450,688 -> 108,347,392
    u16*   p12  = (u16*)  (ws + 108347392);   //  8,028,160 -> 116,375,552
    u16*   p16  = (u16*)  (ws + 116375552);   //  1,605,632 -> 117,981,184
    float* clsr = (float*)(ws + 117981184);   //  5,268,480 -> 123,249,664
    u16*   whd  = (u16*)  (ws + 123249728);   //  2,488,320 -> 125,738,048
    float* bfs  = (float*)(ws + 125738048);   //     11,768

    u16* w_cls_b  = whd;
    u16* w_b1_b   = whd + 15360;
    u16* w_b34_b  = whd + 506880;
    u16* w_b2_b   = whd + 875520;
    u16* w_b4_b   = whd + 1121280;

    zero_halo<<<1828, 256, 0, stream>>>(xpad);
    pad_fill<<<7168, 256, 0, stream>>>(base_feat, xpad, im_info);
    wt_transform<<<1024, 256, 0, stream>>>(W_conv, wt, im_info);
    cvt_all<<<4873, 256, 0, stream>>>(W_cls, W_bbox, W_bbox34, W_bbox2, W_bbox4,
                                      b_conv, b_cls, b_bbox, b_bbox34, b_bbox2,
                                      b_bbox4, whd, bfs, im_info);

    conv_gemm256<<<196, 512, 0, stream>>>(xpad, wt, bfs, y);

    pool_all<<<784, 256, 0, stream>>>(y, p4, p8, p12, p16);

    heads_gemm<<<1400, 256, 0, stream>>>(p16, p12, p8, p4,
                                         w_cls_b, w_b1_b, w_b34_b, w_b2_b, w_b4_b,
                                         bfs, clsr, d_out, im_info);

    softmax_all<<<2573, 256, 0, stream>>>(clsr, d_out, im_info);
}

// Round 11
// 562.275 us; speedup vs baseline: 1.2649x; 1.0126x over previous
//
#include <hip/hip_runtime.h>

typedef unsigned short u16;
typedef unsigned int   u32;
typedef __bf16  bf16x8 __attribute__((ext_vector_type(8)));
typedef float   f32x4  __attribute__((ext_vector_type(4)));

__device__ __forceinline__ float bf2f(u16 u) {
    u32 v = ((u32)u) << 16;
    return __builtin_bit_cast(float, v);
}
__device__ __forceinline__ u16 f2bf(float f) {
    u32 u = __builtin_bit_cast(u32, f);
    return (u16)((u + 0x7FFFu + ((u >> 16) & 1u)) >> 16);   // RNE
}
__device__ __forceinline__ float ldf(const void* p, long i, int f32) {
    return f32 ? ((const float*)p)[i] : bf2f(((const u16*)p)[i]);
}
__device__ __forceinline__ int is_f32(const u32* im) {
    return im[0] == 0x43E00000u;   // 448.0f fp32 vs packed bf16 (0x43E043E0)
}
// async global->LDS, 16B per lane (LDS dst = wave-uniform base + lane*16)
__device__ __forceinline__ void gl2lds16(const u16* g, u16* l) {
    __builtin_amdgcn_global_load_lds(
        (const __attribute__((address_space(1))) void*)g,
        (__attribute__((address_space(3))) void*)l, 16, 0, 0);
}

// ------------------------------ pad+transpose base_feat + zero halo (merged)
// Blocks >= 7168 zero the 7.5 MB pad halo (disjoint from interior fill;
// block-uniform branch so the pad path's __syncthreads is legal).
__global__ void pad_zero_fill(const void* __restrict__ src, u16* __restrict__ xpad,
                              const u32* __restrict__ im)
{
    __shared__ u16 lds[56 * 40];
    if (blockIdx.x >= 7168) {
        int i = (blockIdx.x - 7168) * 256 + threadIdx.x;
        if (i < 230400) {                       // t in {0,17}: 2b*2t*900*64
            int c8 = i & 63; int pos = i >> 6;
            int p = pos % 900; pos /= 900;
            int t = (pos & 1) * 17; int b = pos >> 1;
            long o = (((long)(b * 18 + t) * 900) + p) * 512 + c8 * 8;
            *(uint4*)&xpad[o] = uint4{0u, 0u, 0u, 0u};
            return;
        }
        i -= 230400;
        if (i < 122880) {                       // t 1..16, h in {0,29}
            int c8 = i & 63; int pos = i >> 6;
            int w = pos % 30; pos /= 30;
            int h = (pos & 1) * 29; pos >>= 1;
            int t = pos % 16 + 1; int b = pos / 16;
            long o = ((((long)(b * 18 + t) * 30 + h) * 30) + w) * 512 + c8 * 8;
            *(uint4*)&xpad[o] = uint4{0u, 0u, 0u, 0u};
            return;
        }
        i -= 122880;
        if (i < 114688) {                       // t 1..16, h 1..28, w in {0,29}
            int c8 = i & 63; int pos = i >> 6;
            int w = (pos & 1) * 29; pos >>= 1;
            int h = pos % 28 + 1; pos /= 28;
            int t = pos % 16 + 1; int b = pos / 16;
            long o = ((((long)(b * 18 + t) * 30 + h) * 30) + w) * 512 + c8 * 8;
            *(uint4*)&xpad[o] = uint4{0u, 0u, 0u, 0u};
        }
        return;
    }
    const int f32 = is_f32(im);
    int blk = blockIdx.x;
    const int h2  = blk % 14;  blk /= 14;
    const int c32 = blk & 15;  blk >>= 4;
    const int t   = blk & 15;
    const int b   = blk >> 4;
    const int tid = threadIdx.x;
    const long sbase = ((long)(b * 512 + c32 * 32) * 16 + t) * 784 + h2 * 56;
    #pragma unroll
    for (int it = tid; it < 1792; it += 256) {
        const int c = it / 56, p = it - c * 56;
        float v = f32 ? ((const float*)src)[sbase + (long)c * 12544 + p]
                      : bf2f(((const u16*)src)[sbase + (long)c * 12544 + p]);
        lds[p * 40 + c] = f2bf(v);
    }
    __syncthreads();
    if (tid < 224) {
        const int p = tid >> 2, g = tid & 3;
        const int h = h2 * 2 + p / 28, w = p % 28;
        const long o = (((long)(b * 18 + t + 1) * 30 + h + 1) * 30 + (w + 1)) * 512
                       + c32 * 32 + g * 8;
        *(uint4*)&xpad[o] = *(const uint4*)&lds[p * 40 + g * 8];
    }
}

// ------------------------------------------------- W_conv [O][I][27] -> Wt[27][O][I]
__global__ void wt_transform(const void* __restrict__ wconv, u16* __restrict__ wt,
                             const u32* __restrict__ im)
{
    const int f32 = is_f32(im);
    __shared__ u16 lds[256 * 28];
    const int tid = threadIdx.x;
    const int pair_base = blockIdx.x * 256;
    const long s0 = (long)pair_base * 27;
    for (int it = tid; it < 256 * 27; it += 256) {
        const int p = it / 27, o = it - p * 27;
        float v = f32 ? ((const float*)wconv)[s0 + it]
                      : bf2f(((const u16*)wconv)[s0 + it]);
        lds[p * 28 + o] = f2bf(v);
    }
    __syncthreads();
    #pragma unroll
    for (int off = 0; off < 27; ++off)
        wt[(long)off * 262144 + pair_base + tid] = lds[tid * 28 + off];
}

// ------------------------------------------------- head weights + biases (merged)
__global__ void cvt_all(const void* s0, const void* s1, const void* s2,
                        const void* s3, const void* s4,
                        const void* b0, const void* b1, const void* b2,
                        const void* b3, const void* b4, const void* b5,
                        u16* __restrict__ whd, float* __restrict__ bfs,
                        const u32* __restrict__ im)
{
    const int f32 = is_f32(im);
    int i = blockIdx.x * 256 + threadIdx.x;
    if (i < 1244160) {
        const void* s; long j;
        if      (i < 15360)   { s = s0; j = i; }
        else if (i < 506880)  { s = s1; j = i - 15360; }
        else if (i < 875520)  { s = s2; j = i - 506880; }
        else if (i < 1121280) { s = s3; j = i - 875520; }
        else                  { s = s4; j = i - 1121280; }
        whd[i] = f2bf(ldf(s, j, f32));
        return;
    }
    i -= 1244160;
    if (i >= 2942) return;
    float v;
    if      (i < 512)  v = ldf(b0, i, f32);
    else if (i < 542)  v = ldf(b1, i - 512, f32);
    else if (i < 1502) v = ldf(b2, i - 542, f32);
    else if (i < 2222) v = ldf(b3, i - 1502, f32);
    else if (i < 2702) v = ldf(b4, i - 2222, f32);
    else               v = ldf(b5, i - 2702, f32);
    bfs[i] = v;
}

// ---------------------------------------------------------------- conv GEMM (R8, proven 341-347us)
// 256x256 tile, BK=64, ring-2 LDS (2 x 64 KB), ONE barrier + ONE vmcnt(0)
// per 64-K tile (216 total). 16x16x32 MFMA (32x32x16 regressed twice: R9
// bank conflicts, R10 FETCH+30%). 8-slot XOR swizzle; 0 conflicts measured.
__global__ __launch_bounds__(512, 2) void conv_gemm256(
    const u16* __restrict__ xpad, const u16* __restrict__ wt,
    const float* __restrict__ bfs, u16* __restrict__ y)
{
    __shared__ u16 smem[65536];           // 2 bufs x (A 16384 + B 16384) u16
    const int tid = threadIdx.x;

    // bijective XCD remap (m204, nwg=196), pair-major so (n,m0),(n,m1) co-XCD
    const int bx  = blockIdx.x;
    const int xcd = bx & 7, pos = bx >> 3;
    const int L   = (xcd < 4 ? xcd * 25 : 100 + (xcd - 4) * 24) + pos;
    const int m_base = (L & 1) * 256;
    const int n_base = (L >> 1) * 256;

    // staging: granule g = j*512 + tid; row = g>>3; lds slot = tid&7;
    // source slot = (tid&7) ^ (row&7)  (j-independent)
    const int rq8 = tid >> 3;                                   // 0..63
    const int sw  = (((tid & 7) ^ (rq8 & 7))) * 8;              // src col elems
    const u16* pa = wt + (long)(m_base + rq8) * 512 + sw;       // +j*32768 +aoff

    long sbj[4];
    #pragma unroll
    for (int j = 0; j < 4; ++j) {
        const int n = n_base + j * 64 + rq8;
        int b = n / 12544, r = n % 12544;
        int t = r / 784,   q = r % 784;
        int h = q / 28,    w = q % 28;
        const int sa = ((b * 18 + t) * 30 + h) * 30 + w;
        sbj[j] = (long)sa * 512 + sw;
    }

    // read-side identities
    const int lane = tid & 63, wid = tid >> 6;
    const int l16 = lane & 15, quad = lane >> 4;
    const int wm = wid >> 2;              // 0..1 -> 128 rows
    const int wn = wid & 3;               // 0..3 -> 64 cols
    const int x7 = l16 & 7;
    const int o0 = (quad ^ x7) * 8;             // sub0 k-slot (k 0..31)
    const int o1 = ((4 + quad) ^ x7) * 8;       // sub1 k-slot (k 32..63)
    int rowA[8], rowB[4];
    #pragma unroll
    for (int mi = 0; mi < 8; ++mi) rowA[mi] = (wm * 128 + mi * 16 + l16) * 64;
    #pragma unroll
    for (int ni = 0; ni < 4; ++ni) rowB[ni] = 16384 + (wn * 64 + ni * 16 + l16) * 64;

    f32x4 acc[8][4] = {};

    // prologue: stage tile 0 (tap 0, kc 0)
    {
        u16* dst = smem;
        #pragma unroll
        for (int j = 0; j < 4; ++j)
            gl2lds16(pa + (long)j * 32768, dst + j * 4096 + tid * 8);
        #pragma unroll
        for (int j = 0; j < 4; ++j)
            gl2lds16(xpad + sbj[j], dst + 16384 + j * 4096 + tid * 8);
    }

    for (int kt = 0; kt < 216; ++kt) {
        asm volatile("s_waitcnt vmcnt(0)" ::: "memory");
        asm volatile("s_barrier" ::: "memory");
        const u16* buf = smem + (kt & 1) * 32768;

        bf16x8 af[8], bfr[4];
        #pragma unroll
        for (int mi = 0; mi < 4; ++mi)
            af[mi] = *(const bf16x8*)&buf[rowA[mi] + o0];
        #pragma unroll
        for (int ni = 0; ni < 4; ++ni)
            bfr[ni] = *(const bf16x8*)&buf[rowB[ni] + o0];
        #pragma unroll
        for (int mi = 4; mi < 8; ++mi)
            af[mi] = *(const bf16x8*)&buf[rowA[mi] + o0];

        if (kt < 215) {
            const int kts = kt + 1;
            const int tap = kts >> 3, kc = kts & 7;
            const int kd = tap / 9, r9 = tap - kd * 9;
            const int kh = r9 / 3,  kw = r9 - kh * 3;
            const long aoff = (long)tap * 262144 + kc * 64;
            const long boff = (long)(kd * 900 + kh * 30 + kw) * 512 + kc * 64;
            u16* dst = smem + ((kts & 1) << 15);
            #pragma unroll
            for (int j = 0; j < 4; ++j)
                gl2lds16(pa + aoff + (long)j * 32768, dst + j * 4096 + tid * 8);
            #pragma unroll
            for (int j = 0; j < 4; ++j)
                gl2lds16(xpad + sbj[j] + boff, dst + 16384 + j * 4096 + tid * 8);
        }

        __builtin_amdgcn_s_setprio(1);
        #pragma unroll
        for (int mi = 0; mi < 8; ++mi)
            #pragma unroll
            for (int ni = 0; ni < 4; ++ni)
                acc[mi][ni] = __builtin_amdgcn_mfma_f32_16x16x32_bf16(
                    af[mi], bfr[ni], acc[mi][ni], 0, 0, 0);
        __builtin_amdgcn_s_setprio(0);

        bf16x8 ag[8], bgr[4];
        #pragma unroll
        for (int mi = 0; mi < 8; ++mi)
            ag[mi] = *(const bf16x8*)&buf[rowA[mi] + o1];
        #pragma unroll
        for (int ni = 0; ni < 4; ++ni)
            bgr[ni] = *(const bf16x8*)&buf[rowB[ni] + o1];

        __builtin_amdgcn_s_setprio(1);
        #pragma unroll
        for (int mi = 0; mi < 8; ++mi)
            #pragma unroll
            for (int ni = 0; ni < 4; ++ni)
                acc[mi][ni] = __builtin_amdgcn_mfma_f32_16x16x32_bf16(
                    ag[mi], bgr[ni], acc[mi][ni], 0, 0, 0);
        __builtin_amdgcn_s_setprio(0);
    }

    // epilogue: bias + relu + bf16 store to y[n][512]
    #pragma unroll
    for (int mi = 0; mi < 8; ++mi) {
        const int mrow = m_base + wm * 128 + mi * 16 + quad * 4;
        float bias[4];
        #pragma unroll
        for (int r = 0; r < 4; ++r) bias[r] = bfs[mrow + r];
        #pragma unroll
        for (int ni = 0; ni < 4; ++ni) {
            const int ng = n_base + wn * 64 + ni * 16 + l16;
            f32x4 a = acc[mi][ni];
            u16 o0v = f2bf(fmaxf(a[0] + bias[0], 0.f));
            u16 o1v = f2bf(fmaxf(a[1] + bias[1], 0.f));
            u16 o2v = f2bf(fmaxf(a[2] + bias[2], 0.f));
            u16 o3v = f2bf(fmaxf(a[3] + bias[3], 0.f));
            uint2 pv;
            pv.x = (u32)o0v | ((u32)o1v << 16);
            pv.y = (u32)o2v | ((u32)o3v << 16);
            *(uint2*)&y[(long)ng * 512 + mrow] = pv;
        }
    }
}

// ---------------------------------------------------------------- fused pools
__device__ __forceinline__ uint2 max4(uint2 A, uint2 Bv)
{
    const u16* a = (const u16*)&A;
    const u16* b = (const u16*)&Bv;
    uint2 R;
    u16* r = (u16*)&R;
    #pragma unroll
    for (int i = 0; i < 4; ++i) r[i] = (bf2f(a[i]) >= bf2f(b[i])) ? a[i] : b[i];
    return R;
}

// One thread owns (b,hw,c4): loads 16 t-slices (uint2 = 4 bf16), computes all
// four temporal pools via a sliding-max tree in registers, writes 13+9+5+1
// outputs. Reads y exactly once (25.7 MB). 200704 threads / 784 blocks.
__global__ void pool_all(const u16* __restrict__ y, u16* __restrict__ p4,
                         u16* __restrict__ p8, u16* __restrict__ p12,
                         u16* __restrict__ p16)
{
    int g = blockIdx.x * 256 + threadIdx.x;
    if (g >= 200704) return;                 // 2*784*128
    const int c4 = g & 127;
    int pos = g >> 7;
    const int hw = pos % 784; const int b = pos / 784;
    const u16* src = y + ((long)(b * 16) * 784 + hw) * 512 + c4 * 4;
    uint2 v[16];
    #pragma unroll
    for (int t = 0; t < 16; ++t)
        v[t] = *(const uint2*)(src + (long)t * 401408);
    uint2 pr[15];
    #pragma unroll
    for (int t = 0; t < 15; ++t) pr[t] = max4(v[t], v[t + 1]);
    uint2 qd[13];
    #pragma unroll
    for (int t = 0; t < 13; ++t) qd[t] = max4(pr[t], pr[t + 2]);
    uint2 e8[9];
    #pragma unroll
    for (int t = 0; t < 9; ++t) e8[t] = max4(qd[t], qd[t + 4]);
    uint2 e12[5];
    #pragma unroll
    for (int t = 0; t < 5; ++t) e12[t] = max4(e8[t], qd[t + 8]);
    uint2 e16 = max4(e8[0], e8[8]);

    const long col = (long)hw * 512 + c4 * 4;
    #pragma unroll
    for (int t = 0; t < 13; ++t)
        *(uint2*)&p4[((long)(b * 13 + t) * 784) * 512 + col] = qd[t];
    #pragma unroll
    for (int t = 0; t < 9; ++t)
        *(uint2*)&p8[((long)(b * 9 + t) * 784) * 512 + col] = e8[t];
    #pragma unroll
    for (int t = 0; t < 5; ++t)
        *(uint2*)&p12[((long)(b * 5 + t) * 784) * 512 + col] = e12[t];
    *(uint2*)&p16[((long)b * 784) * 512 + col] = e16;
}

// ---------------------------------------------------------------- fused heads GEMM (R12b)
// Ring-3 of BK=32 (3 x 16 KB = 48 KB LDS, still 2 blocks/CU) with counted
// vmcnt(4): each stage batch = 4 gl2lds per thread (2 A + 2 B). At step kc's
// gate, outstanding = batch kc (4, issued 2 steps ago) + batch kc+1 (4,
// issued 1 step ago); vmcnt(4) retires exactly batch kc -- the buffer about
// to be read -- keeping batch kc+1 in flight across the barrier (2-step
// prefetch distance). [R10's vmcnt(8) was a no-op gate -> NaN.]
// Pair-softmax FUSED into mt==0 blocks: cls rows 0..29 staged in LDS
// (reused ring buffers after __syncthreads), probs written straight to out.
__global__ __launch_bounds__(256, 2) void heads_gemm(
    const u16* __restrict__ p16, const u16* __restrict__ p12,
    const u16* __restrict__ p8,  const u16* __restrict__ p4,
    const u16* __restrict__ wcls, const u16* __restrict__ wb1,
    const u16* __restrict__ wb34, const u16* __restrict__ wb2,
    const u16* __restrict__ wb4,  const float* __restrict__ bfs,
    void* __restrict__ outv, const u32* __restrict__ im)
{
    const int f32 = is_f32(im);
    int bid = blockIdx.x;
    const u16* pool; const u16* wbp; int Ti, CH, nt, mt; long boff, coff, ooff;
    if (bid < 104)      {             nt = bid % 13;  mt = bid / 13;  pool = p16; wbp = wb1;  Ti = 1;  CH = 960; boff = 542;  coff = 0;      ooff = 1317120; }
    else if (bid < 476) { bid -= 104; nt = bid % 62;  mt = bid / 62;  pool = p12; wbp = wb34; Ti = 5;  CH = 720; boff = 1502; coff = 47040;  ooff = 2822400; }
    else if (bid < 920) { bid -= 476; nt = bid % 111; mt = bid / 111; pool = p8;  wbp = wb2;  Ti = 9;  CH = 480; boff = 2222; coff = 282240; ooff = 8467200; }
    else                { bid -= 920; nt = bid % 160; mt = bid / 160; pool = p4;  wbp = wb4;  Ti = 13; CH = 240; boff = 2702; coff = 705600; ooff = 15240960; }
    const int M = 30 + CH;
    const int THW = Ti * 784;
    const int N = 2 * THW;
    const int n_base = nt * 128;
    const int m_base = mt * 128;

    __shared__ u16 lds[24576];               // 3 bufs x (A 4096 + B 4096) u16
    const int tid = threadIdx.x;
    const int lane = tid & 63;
    const int wid  = tid >> 6;
    const int quad = lane >> 4;
    const int l16  = lane & 15;
    const int wm = (wid & 1) * 64;
    const int wn = (wid >> 1) * 64;

    // staging: row = i*64 + (tid>>2); src chunk kk = ((tid&3)^((tid>>3)&3))*8
    const int srow = tid >> 2;            // 0..63, + i*64
    const int kk   = (((tid & 3) ^ ((tid >> 3) & 3))) * 8;

    const u16* arow[2]; const u16* brow[2];
    #pragma unroll
    for (int i = 0; i < 2; ++i) {
        int m = m_base + i * 64 + srow; if (m > M - 1) m = M - 1;
        arow[i] = ((m < 30) ? (wcls + m * 512) : (wbp + (m - 30) * 512)) + kk;
        int n = n_base + i * 64 + srow; if (n > N - 1) n = N - 1;
        brow[i] = pool + (long)n * 512 + kk;
    }

    // read offsets: row*32 elems + swizzled 16B slot
    const int co = (quad ^ ((l16 >> 1) & 3)) * 8;
    int rowA[4], rowB[4];
    #pragma unroll
    for (int i = 0; i < 4; ++i) {
        rowA[i] = (wm + i * 16 + l16) * 32 + co;
        rowB[i] = 4096 + (wn + i * 16 + l16) * 32 + co;
    }

    // prologue: stage kc0 -> buf0, kc1 -> buf1 (8 loads/thread in flight)
    #pragma unroll
    for (int i = 0; i < 2; ++i)
        gl2lds16(arow[i], &lds[i * 2048 + tid * 8]);
    #pragma unroll
    for (int i = 0; i < 2; ++i)
        gl2lds16(brow[i], &lds[4096 + i * 2048 + tid * 8]);
    #pragma unroll
    for (int i = 0; i < 2; ++i)
        gl2lds16(arow[i] + 32, &lds[8192 + i * 2048 + tid * 8]);
    #pragma unroll
    for (int i = 0; i < 2; ++i)
        gl2lds16(brow[i] + 32, &lds[8192 + 4096 + i * 2048 + tid * 8]);

    f32x4 acc[4][4] = {};
    int cb = 0;
    for (int kc = 0; kc < 15; ++kc) {
        asm volatile("s_waitcnt vmcnt(4)" ::: "memory");
        asm volatile("s_barrier" ::: "memory");
        const u16* buf = lds + cb * 8192;
        bf16x8 af[4], bfr[4];
        #pragma unroll
        for (int mi = 0; mi < 4; ++mi)
            af[mi]  = *(const bf16x8*)&buf[rowA[mi]];
        #pragma unroll
        for (int ni = 0; ni < 4; ++ni)
            bfr[ni] = *(const bf16x8*)&buf[rowB[ni]];
        if (kc < 14) {
            const int kcol = (kc + 2) * 32;
            int nb = cb + 2; if (nb >= 3) nb -= 3;
            u16* dst = lds + nb * 8192 + tid * 8;
            #pragma unroll
            for (int i = 0; i < 2; ++i)
                gl2lds16(arow[i] + kcol, dst + i * 2048);
            #pragma unroll
            for (int i = 0; i < 2; ++i)
                gl2lds16(brow[i] + kcol, dst + 4096 + i * 2048);
        }
        __builtin_amdgcn_s_setprio(1);
        #pragma unroll
        for (int mi = 0; mi < 4; ++mi)
            #pragma unroll
            for (int ni = 0; ni < 4; ++ni)
                acc[mi][ni] = __builtin_amdgcn_mfma_f32_16x16x32_bf16(
                    af[mi], bfr[ni], acc[mi][ni], 0, 0, 0);
        __builtin_amdgcn_s_setprio(0);
        cb = (cb + 1 == 3) ? 0 : cb + 1;
    }
    {   // final step kc=15
        asm volatile("s_waitcnt vmcnt(0)" ::: "memory");
        asm volatile("s_barrier" ::: "memory");
        const u16* buf = lds + cb * 8192;
        bf16x8 af[4], bfr[4];
        #pragma unroll
        for (int mi = 0; mi < 4; ++mi)
            af[mi]  = *(const bf16x8*)&buf[rowA[mi]];
        #pragma unroll
        for (int ni = 0; ni < 4; ++ni)
            bfr[ni] = *(const bf16x8*)&buf[rowB[ni]];
        #pragma unroll
        for (int mi = 0; mi < 4; ++mi)
            #pragma unroll
            for (int ni = 0; ni < 4; ++ni)
                acc[mi][ni] = __builtin_amdgcn_mfma_f32_16x16x32_bf16(
                    af[mi], bfr[ni], acc[mi][ni], 0, 0, 0);
    }

    // ---- epilogue: bbox -> global; cls -> LDS (mt==0) then fused softmax
    __syncthreads();                         // all LDS reads of ring done
    float* smf = (float*)lds;                // 30 x 128 f32 = 15360 B
    const float* bcls = bfs + 512;
    const float* bb   = bfs + boff;
    #pragma unroll
    for (int mi = 0; mi < 4; ++mi) {
        const int mrow = m_base + wm + mi * 16 + quad * 4;
        #pragma unroll
        for (int ni = 0; ni < 4; ++ni) {
            const int ng = n_base + wn + ni * 16 + l16;
            if (ng >= N) continue;
            const int b  = ng / THW;
            const int rr = ng % THW;
            f32x4 a = acc[mi][ni];
            #pragma unroll
            for (int r = 0; r < 4; ++r) {
                const int m = mrow + r;
                if (m >= M) break;
                if (m < 30) {
                    smf[m * 128 + (wn + ni * 16 + l16)] = a[r] + bcls[m];
                } else {
                    const float v = a[r] + bb[m - 30];
                    const long oi = ooff + ((long)(b * CH + (m - 30))) * THW + rr;
                    if (f32) ((float*)outv)[oi] = v;
                    else     ((u16*)outv)[oi]   = f2bf(v);
                }
            }
        }
    }
    __syncthreads();
    if (m_base == 0) {
        for (int p = tid; p < 1920; p += 256) {
            const int j = p >> 7, col = p & 127;
            const int ng = n_base + col;
            if (ng >= N) continue;
            const float s0 = smf[j * 128 + col];
            const float s1 = smf[(j + 15) * 128 + col];
            const float mx = fmaxf(s0, s1);
            const float e0 = __expf(s0 - mx), e1 = __expf(s1 - mx);
            const float inv = 1.0f / (e0 + e1);
            const int b = ng / THW, rr = ng % THW;
            const long i0 = coff + ((long)(b * 30 + j)) * THW + rr;
            const long i1 = coff + ((long)(b * 30 + j + 15)) * THW + rr;
            if (f32) {
                ((float*)outv)[i0] = e0 * inv;
                ((float*)outv)[i1] = e1 * inv;
            } else {
                ((u16*)outv)[i0] = f2bf(e0 * inv);
                ((u16*)outv)[i1] = f2bf(e1 * inv);
            }
        }
    }
}

// ---------------------------------------------------------------- launcher
extern "C" void kernel_launch(void* const* d_in, const int* in_sizes, int n_in,
                              void* d_out, int out_size, void* d_ws, size_t ws_size,
                              hipStream_t stream)
{
    const void* base_feat = d_in[0];
    const u32*  im_info   = (const u32*)d_in[1];
    const void* W_conv    = d_in[4];
    const void* b_conv    = d_in[5];
    const void* W_cls     = d_in[6];
    const void* b_cls     = d_in[7];
    const void* W_bbox    = d_in[8];
    const void* b_bbox    = d_in[9];
    const void* W_bbox34  = d_in[10];
    const void* b_bbox34  = d_in[11];
    const void* W_bbox2   = d_in[12];
    const void* b_bbox2   = d_in[13];
    const void* W_bbox4   = d_in[14];
    const void* b_bbox4   = d_in[15];

    char* ws = (char*)d_ws;
    u16*   xpad = (u16*)  (ws + 0);           // 33,177,600
    u16*   wt   = (u16*)  (ws + 33177600);    // 14,155,776 -> 47,333,376
    u16*   y    = (u16*)  (ws + 47333376);    // 25,690,112 -> 73,023,488
    u16*   p4   = (u16*)  (ws + 73023488);    // 20,873,216 -> 93,896,704
    u16*   p8   = (u16*)  (ws + 93896704);    // 14,450,688 -> 108,347,392
    u16*   p12  = (u16*)  (ws + 108347392);   //  8,028,160 -> 116,375,552
    u16*   p16  = (u16*)  (ws + 116375552);   //  1,605,632 -> 117,981,184
    u16*   whd  = (u16*)  (ws + 123249728);   //  2,488,320 -> 125,738,048
    float* bfs  = (float*)(ws + 125738048);   //     11,768

    u16* w_cls_b  = whd;
    u16* w_b1_b   = whd + 15360;
    u16* w_b34_b  = whd + 506880;
    u16* w_b2_b   = whd + 875520;
    u16* w_b4_b   = whd + 1121280;

    pad_zero_fill<<<8996, 256, 0, stream>>>(base_feat, xpad, im_info);
    wt_transform<<<1024, 256, 0, stream>>>(W_conv, wt, im_info);
    cvt_all<<<4873, 256, 0, stream>>>(W_cls, W_bbox, W_bbox34, W_bbox2, W_bbox4,
                                      b_conv, b_cls, b_bbox, b_bbox34, b_bbox2,
                                      b_bbox4, whd, bfs, im_info);

    conv_gemm256<<<196, 512, 0, stream>>>(xpad, wt, bfs, y);

    pool_all<<<784, 256, 0, stream>>>(y, p4, p8, p12, p16);

    heads_gemm<<<1400, 256, 0, stream>>>(p16, p12, p8, p4,
                                         w_cls_b, w_b1_b, w_b34_b, w_b2_b, w_b4_b,
                                         bfs, d_out, im_info);
}

// Round 12
// 541.926 us; speedup vs baseline: 1.3124x; 1.0375x over previous
//
#include <hip/hip_runtime.h>

typedef unsigned short u16;
typedef unsigned int   u32;
typedef __bf16  bf16x8 __attribute__((ext_vector_type(8)));
typedef float   f32x4  __attribute__((ext_vector_type(4)));

__device__ __forceinline__ float bf2f(u16 u) {
    u32 v = ((u32)u) << 16;
    return __builtin_bit_cast(float, v);
}
__device__ __forceinline__ u16 f2bf(float f) {
    u32 u = __builtin_bit_cast(u32, f);
    return (u16)((u + 0x7FFFu + ((u >> 16) & 1u)) >> 16);   // RNE
}
__device__ __forceinline__ float ldf(const void* p, long i, int f32) {
    return f32 ? ((const float*)p)[i] : bf2f(((const u16*)p)[i]);
}
__device__ __forceinline__ int is_f32(const u32* im) {
    return im[0] == 0x43E00000u;   // 448.0f fp32 vs packed bf16 (0x43E043E0)
}
// async global->LDS, 16B per lane (LDS dst = wave-uniform base + lane*16)
__device__ __forceinline__ void gl2lds16(const u16* g, u16* l) {
    __builtin_amdgcn_global_load_lds(
        (const __attribute__((address_space(1))) void*)g,
        (__attribute__((address_space(3))) void*)l, 16, 0, 0);
}

// ------------------------------ pad+transpose base_feat + zero halo (merged)
__global__ void pad_zero_fill(const void* __restrict__ src, u16* __restrict__ xpad,
                              const u32* __restrict__ im)
{
    __shared__ u16 lds[56 * 40];
    if (blockIdx.x >= 7168) {
        int i = (blockIdx.x - 7168) * 256 + threadIdx.x;
        if (i < 230400) {                       // t in {0,17}: 2b*2t*900*64
            int c8 = i & 63; int pos = i >> 6;
            int p = pos % 900; pos /= 900;
            int t = (pos & 1) * 17; int b = pos >> 1;
            long o = (((long)(b * 18 + t) * 900) + p) * 512 + c8 * 8;
            *(uint4*)&xpad[o] = uint4{0u, 0u, 0u, 0u};
            return;
        }
        i -= 230400;
        if (i < 122880) {                       // t 1..16, h in {0,29}
            int c8 = i & 63; int pos = i >> 6;
            int w = pos % 30; pos /= 30;
            int h = (pos & 1) * 29; pos >>= 1;
            int t = pos % 16 + 1; int b = pos / 16;
            long o = ((((long)(b * 18 + t) * 30 + h) * 30) + w) * 512 + c8 * 8;
            *(uint4*)&xpad[o] = uint4{0u, 0u, 0u, 0u};
            return;
        }
        i -= 122880;
        if (i < 114688) {                       // t 1..16, h 1..28, w in {0,29}
            int c8 = i & 63; int pos = i >> 6;
            int w = (pos & 1) * 29; pos >>= 1;
            int h = pos % 28 + 1; pos /= 28;
            int t = pos % 16 + 1; int b = pos / 16;
            long o = ((((long)(b * 18 + t) * 30 + h) * 30) + w) * 512 + c8 * 8;
            *(uint4*)&xpad[o] = uint4{0u, 0u, 0u, 0u};
        }
        return;
    }
    const int f32 = is_f32(im);
    int blk = blockIdx.x;
    const int h2  = blk % 14;  blk /= 14;
    const int c32 = blk & 15;  blk >>= 4;
    const int t   = blk & 15;
    const int b   = blk >> 4;
    const int tid = threadIdx.x;
    const long sbase = ((long)(b * 512 + c32 * 32) * 16 + t) * 784 + h2 * 56;
    #pragma unroll
    for (int it = tid; it < 1792; it += 256) {
        const int c = it / 56, p = it - c * 56;
        float v = f32 ? ((const float*)src)[sbase + (long)c * 12544 + p]
                      : bf2f(((const u16*)src)[sbase + (long)c * 12544 + p]);
        lds[p * 40 + c] = f2bf(v);
    }
    __syncthreads();
    if (tid < 224) {
        const int p = tid >> 2, g = tid & 3;
        const int h = h2 * 2 + p / 28, w = p % 28;
        const long o = (((long)(b * 18 + t + 1) * 30 + h + 1) * 30 + (w + 1)) * 512
                       + c32 * 32 + g * 8;
        *(uint4*)&xpad[o] = *(const uint4*)&lds[p * 40 + g * 8];
    }
}

// --------------------- W_conv transform + head weights/biases cvt (merged)
// Blocks 0..1023: Wt[27][O][I] transform (uses LDS + syncthreads).
// Blocks 1024..5896: elementwise head-weight/bias conversion.
__global__ void wt_cvt_all(const void* __restrict__ wconv, u16* __restrict__ wt,
                           const void* s0, const void* s1, const void* s2,
                           const void* s3, const void* s4,
                           const void* b0, const void* b1, const void* b2,
                           const void* b3, const void* b4, const void* b5,
                           u16* __restrict__ whd, float* __restrict__ bfs,
                           const u32* __restrict__ im)
{
    const int f32 = is_f32(im);
    __shared__ u16 lds[256 * 28];
    const int tid = threadIdx.x;
    if (blockIdx.x < 1024) {
        const int pair_base = blockIdx.x * 256;
        const long s0l = (long)pair_base * 27;
        for (int it = tid; it < 256 * 27; it += 256) {
            const int p = it / 27, o = it - p * 27;
            float v = f32 ? ((const float*)wconv)[s0l + it]
                          : bf2f(((const u16*)wconv)[s0l + it]);
            lds[p * 28 + o] = f2bf(v);
        }
        __syncthreads();
        #pragma unroll
        for (int off = 0; off < 27; ++off)
            wt[(long)off * 262144 + pair_base + tid] = lds[tid * 28 + off];
        return;
    }
    int i = (blockIdx.x - 1024) * 256 + tid;
    if (i < 1244160) {
        const void* s; long j;
        if      (i < 15360)   { s = s0; j = i; }
        else if (i < 506880)  { s = s1; j = i - 15360; }
        else if (i < 875520)  { s = s2; j = i - 506880; }
        else if (i < 1121280) { s = s3; j = i - 875520; }
        else                  { s = s4; j = i - 1121280; }
        whd[i] = f2bf(ldf(s, j, f32));
        return;
    }
    i -= 1244160;
    if (i >= 2942) return;
    float v;
    if      (i < 512)  v = ldf(b0, i, f32);
    else if (i < 542)  v = ldf(b1, i - 512, f32);
    else if (i < 1502) v = ldf(b2, i - 542, f32);
    else if (i < 2222) v = ldf(b3, i - 1502, f32);
    else if (i < 2702) v = ldf(b4, i - 2222, f32);
    else               v = ldf(b5, i - 2702, f32);
    bfs[i] = v;
}

// ---------------------------------------------------------------- conv GEMM (R14)
// 256m x 224n tile -> 2 x 112 = 224 blocks (one round on 256 CUs; the old
// 196-block grid idled 60 CUs -- wall ~ 0.875x). BK=64, ring-2 LDS
// (2 x 60 KB = 120 KB, 1 block/CU), R8 schedule: ONE barrier + ONE vmcnt(0)
// per 64-K tile (216 total), 16x16x32 MFMA.
// Waves: 4m x 2n, per-wave 64m x 112n (7 n-frags), acc[4][7].
// LDS swizzle identical family (slot ^ (row&7)); B batch stride 56 = 0 mod 8
// so row&7 = (tid>>3)&7 stays j-invariant on both staging and read sides.
// B staging: 1792 granules = 4 batches x 448 threads (tid<448 is wave-uniform,
// 448 = 7 waves); per-batch per-wave LDS dst base uniform.
__global__ __launch_bounds__(512, 2) void conv_gemm256(
    const u16* __restrict__ xpad, const u16* __restrict__ wt,
    const float* __restrict__ bfs, u16* __restrict__ y)
{
    __shared__ u16 smem[61440];           // 2 bufs x (A 16384 + B 14336) u16
    const int tid = threadIdx.x;

    // bijective XCD remap (nwg=224 = 8*28), pair-major: (n, m0),(n, m1) co-XCD
    const int bx  = blockIdx.x;
    const int L   = (bx & 7) * 28 + (bx >> 3);
    const int m_base = (L & 1) * 256;
    const int n_base = (L >> 1) * 224;

    // staging: lds slot = tid&7; row&7 = (tid>>3)&7 (A: +j*64, B: +b*56)
    const int rq8 = tid >> 3;                                   // 0..63
    const int sw  = (((tid & 7) ^ (rq8 & 7))) * 8;              // src col elems
    const u16* pa = wt + (long)(m_base + rq8) * 512 + sw;       // +j*32768 +aoff

    long sbj[4];
    #pragma unroll
    for (int j = 0; j < 4; ++j) {
        int n = n_base + j * 56 + rq8;
        if (n > 25087) n = 25087;          // tid>=448 never loads B; clamp anyway
        int b = n / 12544, r = n % 12544;
        int t = r / 784,   q = r % 784;
        int h = q / 28,    w = q % 28;
        const int sa = ((b * 18 + t) * 30 + h) * 30 + w;
        sbj[j] = (long)sa * 512 + sw;
    }
    const bool stgB = (tid < 448);

    // read-side identities: 4m x 2n waves
    const int lane = tid & 63, wid = tid >> 6;
    const int l16 = lane & 15, quad = lane >> 4;
    const int wm = wid >> 1;              // 0..3 -> 64-row m group
    const int wn = wid & 1;               // 0..1 -> 112-col n group
    const int x7 = l16 & 7;
    const int o0 = (quad ^ x7) * 8;             // sub0 k-slot (k 0..31)
    const int o1 = ((4 + quad) ^ x7) * 8;       // sub1 k-slot (k 32..63)
    int rowA[4], rowB[7];
    #pragma unroll
    for (int mi = 0; mi < 4; ++mi) rowA[mi] = (wm * 64 + mi * 16 + l16) * 64;
    #pragma unroll
    for (int ni = 0; ni < 7; ++ni) rowB[ni] = 16384 + (wn * 112 + ni * 16 + l16) * 64;

    f32x4 acc[4][7] = {};

    // prologue: stage tile 0 (tap 0, kc 0)
    {
        u16* dst = smem;
        #pragma unroll
        for (int j = 0; j < 4; ++j)
            gl2lds16(pa + (long)j * 32768, dst + j * 4096 + tid * 8);
        if (stgB) {
            #pragma unroll
            for (int j = 0; j < 4; ++j)
                gl2lds16(xpad + sbj[j], dst + 16384 + j * 3584 + tid * 8);
        }
    }

    for (int kt = 0; kt < 216; ++kt) {
        asm volatile("s_waitcnt vmcnt(0)" ::: "memory");
        asm volatile("s_barrier" ::: "memory");
        const u16* buf = smem + (kt & 1) * 30720;

        bf16x8 af[4], bfr[7];
        #pragma unroll
        for (int mi = 0; mi < 4; ++mi)
            af[mi] = *(const bf16x8*)&buf[rowA[mi] + o0];
        #pragma unroll
        for (int ni = 0; ni < 7; ++ni)
            bfr[ni] = *(const bf16x8*)&buf[rowB[ni] + o0];

        if (kt < 215) {
            const int kts = kt + 1;
            const int tap = kts >> 3, kc = kts & 7;
            const int kd = tap / 9, r9 = tap - kd * 9;
            const int kh = r9 / 3,  kw = r9 - kh * 3;
            const long aoff = (long)tap * 262144 + kc * 64;
            const long boff = (long)(kd * 900 + kh * 30 + kw) * 512 + kc * 64;
            u16* dst = smem + (kts & 1) * 30720;
            #pragma unroll
            for (int j = 0; j < 4; ++j)
                gl2lds16(pa + aoff + (long)j * 32768, dst + j * 4096 + tid * 8);
            if (stgB) {
                #pragma unroll
                for (int j = 0; j < 4; ++j)
                    gl2lds16(xpad + sbj[j] + boff, dst + 16384 + j * 3584 + tid * 8);
            }
        }

        __builtin_amdgcn_s_setprio(1);
        #pragma unroll
        for (int mi = 0; mi < 4; ++mi)
            #pragma unroll
            for (int ni = 0; ni < 7; ++ni)
                acc[mi][ni] = __builtin_amdgcn_mfma_f32_16x16x32_bf16(
                    af[mi], bfr[ni], acc[mi][ni], 0, 0, 0);
        __builtin_amdgcn_s_setprio(0);

        bf16x8 ag[4], bgr[7];
        #pragma unroll
        for (int mi = 0; mi < 4; ++mi)
            ag[mi] = *(const bf16x8*)&buf[rowA[mi] + o1];
        #pragma unroll
        for (int ni = 0; ni < 7; ++ni)
            bgr[ni] = *(const bf16x8*)&buf[rowB[ni] + o1];

        __builtin_amdgcn_s_setprio(1);
        #pragma unroll
        for (int mi = 0; mi < 4; ++mi)
            #pragma unroll
            for (int ni = 0; ni < 7; ++ni)
                acc[mi][ni] = __builtin_amdgcn_mfma_f32_16x16x32_bf16(
                    ag[mi], bgr[ni], acc[mi][ni], 0, 0, 0);
        __builtin_amdgcn_s_setprio(0);
    }

    // epilogue: bias + relu + bf16 store to y[n][512]
    #pragma unroll
    for (int mi = 0; mi < 4; ++mi) {
        const int mrow = m_base + wm * 64 + mi * 16 + quad * 4;
        float bias[4];
        #pragma unroll
        for (int r = 0; r < 4; ++r) bias[r] = bfs[mrow + r];
        #pragma unroll
        for (int ni = 0; ni < 7; ++ni) {
            const int ng = n_base + wn * 112 + ni * 16 + l16;
            f32x4 a = acc[mi][ni];
            u16 o0v = f2bf(fmaxf(a[0] + bias[0], 0.f));
            u16 o1v = f2bf(fmaxf(a[1] + bias[1], 0.f));
            u16 o2v = f2bf(fmaxf(a[2] + bias[2], 0.f));
            u16 o3v = f2bf(fmaxf(a[3] + bias[3], 0.f));
            uint2 pv;
            pv.x = (u32)o0v | ((u32)o1v << 16);
            pv.y = (u32)o2v | ((u32)o3v << 16);
            *(uint2*)&y[(long)ng * 512 + mrow] = pv;
        }
    }
}

// ---------------------------------------------------------------- fused pools
__device__ __forceinline__ uint2 max4(uint2 A, uint2 Bv)
{
    const u16* a = (const u16*)&A;
    const u16* b = (const u16*)&Bv;
    uint2 R;
    u16* r = (u16*)&R;
    #pragma unroll
    for (int i = 0; i < 4; ++i) r[i] = (bf2f(a[i]) >= bf2f(b[i])) ? a[i] : b[i];
    return R;
}

// One thread owns (b,hw,c4): loads 16 t-slices (uint2 = 4 bf16), computes all
// four temporal pools via a sliding-max tree in registers, writes 13+9+5+1
// outputs. Reads y exactly once (25.7 MB). 200704 threads / 784 blocks.
__global__ void pool_all(const u16* __restrict__ y, u16* __restrict__ p4,
                         u16* __restrict__ p8, u16* __restrict__ p12,
                         u16* __restrict__ p16)
{
    int g = blockIdx.x * 256 + threadIdx.x;
    if (g >= 200704) return;                 // 2*784*128
    const int c4 = g & 127;
    int pos = g >> 7;
    const int hw = pos % 784; const int b = pos / 784;
    const u16* src = y + ((long)(b * 16) * 784 + hw) * 512 + c4 * 4;
    uint2 v[16];
    #pragma unroll
    for (int t = 0; t < 16; ++t)
        v[t] = *(const uint2*)(src + (long)t * 401408);
    uint2 pr[15];
    #pragma unroll
    for (int t = 0; t < 15; ++t) pr[t] = max4(v[t], v[t + 1]);
    uint2 qd[13];
    #pragma unroll
    for (int t = 0; t < 13; ++t) qd[t] = max4(pr[t], pr[t + 2]);
    uint2 e8[9];
    #pragma unroll
    for (int t = 0; t < 9; ++t) e8[t] = max4(qd[t], qd[t + 4]);
    uint2 e12[5];
    #pragma unroll
    for (int t = 0; t < 5; ++t) e12[t] = max4(e8[t], qd[t + 8]);
    uint2 e16 = max4(e8[0], e8[8]);

    const long col = (long)hw * 512 + c4 * 4;
    #pragma unroll
    for (int t = 0; t < 13; ++t)
        *(uint2*)&p4[((long)(b * 13 + t) * 784) * 512 + col] = qd[t];
    #pragma unroll
    for (int t = 0; t < 9; ++t)
        *(uint2*)&p8[((long)(b * 9 + t) * 784) * 512 + col] = e8[t];
    #pragma unroll
    for (int t = 0; t < 5; ++t)
        *(uint2*)&p12[((long)(b * 5 + t) * 784) * 512 + col] = e12[t];
    *(uint2*)&p16[((long)b * 784) * 512 + col] = e16;
}

// ---------------------------------------------------------------- fused heads GEMM (R12b, proven)
// Ring-3 of BK=32 (3 x 16 KB = 48 KB LDS) with counted vmcnt(4); fused
// pair-softmax in mt==0 blocks.
__global__ __launch_bounds__(256, 2) void heads_gemm(
    const u16* __restrict__ p16, const u16* __restrict__ p12,
    const u16* __restrict__ p8,  const u16* __restrict__ p4,
    const u16* __restrict__ wcls, const u16* __restrict__ wb1,
    const u16* __restrict__ wb34, const u16* __restrict__ wb2,
    const u16* __restrict__ wb4,  const float* __restrict__ bfs,
    void* __restrict__ outv, const u32* __restrict__ im)
{
    const int f32 = is_f32(im);
    int bid = blockIdx.x;
    const u16* pool; const u16* wbp; int Ti, CH, nt, mt; long boff, coff, ooff;
    if (bid < 104)      {             nt = bid % 13;  mt = bid / 13;  pool = p16; wbp = wb1;  Ti = 1;  CH = 960; boff = 542;  coff = 0;      ooff = 1317120; }
    else if (bid < 476) { bid -= 104; nt = bid % 62;  mt = bid / 62;  pool = p12; wbp = wb34; Ti = 5;  CH = 720; boff = 1502; coff = 47040;  ooff = 2822400; }
    else if (bid < 920) { bid -= 476; nt = bid % 111; mt = bid / 111; pool = p8;  wbp = wb2;  Ti = 9;  CH = 480; boff = 2222; coff = 282240; ooff = 8467200; }
    else                { bid -= 920; nt = bid % 160; mt = bid / 160; pool = p4;  wbp = wb4;  Ti = 13; CH = 240; boff = 2702; coff = 705600; ooff = 15240960; }
    const int M = 30 + CH;
    const int THW = Ti * 784;
    const int N = 2 * THW;
    const int n_base = nt * 128;
    const int m_base = mt * 128;

    __shared__ u16 lds[24576];               // 3 bufs x (A 4096 + B 4096) u16
    const int tid = threadIdx.x;
    const int lane = tid & 63;
    const int wid  = tid >> 6;
    const int quad = lane >> 4;
    const int l16  = lane & 15;
    const int wm = (wid & 1) * 64;
    const int wn = (wid >> 1) * 64;

    // staging: row = i*64 + (tid>>2); src chunk kk = ((tid&3)^((tid>>3)&3))*8
    const int srow = tid >> 2;            // 0..63, + i*64
    const int kk   = (((tid & 3) ^ ((tid >> 3) & 3))) * 8;

    const u16* arow[2]; const u16* brow[2];
    #pragma unroll
    for (int i = 0; i < 2; ++i) {
        int m = m_base + i * 64 + srow; if (m > M - 1) m = M - 1;
        arow[i] = ((m < 30) ? (wcls + m * 512) : (wbp + (m - 30) * 512)) + kk;
        int n = n_base + i * 64 + srow; if (n > N - 1) n = N - 1;
        brow[i] = pool + (long)n * 512 + kk;
    }

    // read offsets: row*32 elems + swizzled 16B slot
    const int co = (quad ^ ((l16 >> 1) & 3)) * 8;
    int rowA[4], rowB[4];
    #pragma unroll
    for (int i = 0; i < 4; ++i) {
        rowA[i] = (wm + i * 16 + l16) * 32 + co;
        rowB[i] = 4096 + (wn + i * 16 + l16) * 32 + co;
    }

    // prologue: stage kc0 -> buf0, kc1 -> buf1 (8 loads/thread in flight)
    #pragma unroll
    for (int i = 0; i < 2; ++i)
        gl2lds16(arow[i], &lds[i * 2048 + tid * 8]);
    #pragma unroll
    for (int i = 0; i < 2; ++i)
        gl2lds16(brow[i], &lds[4096 + i * 2048 + tid * 8]);
    #pragma unroll
    for (int i = 0; i < 2; ++i)
        gl2lds16(arow[i] + 32, &lds[8192 + i * 2048 + tid * 8]);
    #pragma unroll
    for (int i = 0; i < 2; ++i)
        gl2lds16(brow[i] + 32, &lds[8192 + 4096 + i * 2048 + tid * 8]);

    f32x4 acc[4][4] = {};
    int cb = 0;
    for (int kc = 0; kc < 15; ++kc) {
        asm volatile("s_waitcnt vmcnt(4)" ::: "memory");
        asm volatile("s_barrier" ::: "memory");
        const u16* buf = lds + cb * 8192;
        bf16x8 af[4], bfr[4];
        #pragma unroll
        for (int mi = 0; mi < 4; ++mi)
            af[mi]  = *(const bf16x8*)&buf[rowA[mi]];
        #pragma unroll
        for (int ni = 0; ni < 4; ++ni)
            bfr[ni] = *(const bf16x8*)&buf[rowB[ni]];
        if (kc < 14) {
            const int kcol = (kc + 2) * 32;
            int nb = cb + 2; if (nb >= 3) nb -= 3;
            u16* dst = lds + nb * 8192 + tid * 8;
            #pragma unroll
            for (int i = 0; i < 2; ++i)
                gl2lds16(arow[i] + kcol, dst + i * 2048);
            #pragma unroll
            for (int i = 0; i < 2; ++i)
                gl2lds16(brow[i] + kcol, dst + 4096 + i * 2048);
        }
        __builtin_amdgcn_s_setprio(1);
        #pragma unroll
        for (int mi = 0; mi < 4; ++mi)
            #pragma unroll
            for (int ni = 0; ni < 4; ++ni)
                acc[mi][ni] = __builtin_amdgcn_mfma_f32_16x16x32_bf16(
                    af[mi], bfr[ni], acc[mi][ni], 0, 0, 0);
        __builtin_amdgcn_s_setprio(0);
        cb = (cb + 1 == 3) ? 0 : cb + 1;
    }
    {   // final step kc=15
        asm volatile("s_waitcnt vmcnt(0)" ::: "memory");
        asm volatile("s_barrier" ::: "memory");
        const u16* buf = lds + cb * 8192;
        bf16x8 af[4], bfr[4];
        #pragma unroll
        for (int mi = 0; mi < 4; ++mi)
            af[mi]  = *(const bf16x8*)&buf[rowA[mi]];
        #pragma unroll
        for (int ni = 0; ni < 4; ++ni)
            bfr[ni] = *(const bf16x8*)&buf[rowB[ni]];
        #pragma unroll
        for (int mi = 0; mi < 4; ++mi)
            #pragma unroll
            for (int ni = 0; ni < 4; ++ni)
                acc[mi][ni] = __builtin_amdgcn_mfma_f32_16x16x32_bf16(
                    af[mi], bfr[ni], acc[mi][ni], 0, 0, 0);
    }

    // ---- epilogue: bbox -> global; cls -> LDS (mt==0) then fused softmax
    __syncthreads();                         // all LDS reads of ring done
    float* smf = (float*)lds;                // 30 x 128 f32 = 15360 B
    const float* bcls = bfs + 512;
    const float* bb   = bfs + boff;
    #pragma unroll
    for (int mi = 0; mi < 4; ++mi) {
        const int mrow = m_base + wm + mi * 16 + quad * 4;
        #pragma unroll
        for (int ni = 0; ni < 4; ++ni) {
            const int ng = n_base + wn + ni * 16 + l16;
            if (ng >= N) continue;
            const int b  = ng / THW;
            const int rr = ng % THW;
            f32x4 a = acc[mi][ni];
            #pragma unroll
            for (int r = 0; r < 4; ++r) {
                const int m = mrow + r;
                if (m >= M) break;
                if (m < 30) {
                    smf[m * 128 + (wn + ni * 16 + l16)] = a[r] + bcls[m];
                } else {
                    const float v = a[r] + bb[m - 30];
                    const long oi = ooff + ((long)(b * CH + (m - 30))) * THW + rr;
                    if (f32) ((float*)outv)[oi] = v;
                    else     ((u16*)outv)[oi]   = f2bf(v);
                }
            }
        }
    }
    __syncthreads();
    if (m_base == 0) {
        for (int p = tid; p < 1920; p += 256) {
            const int j = p >> 7, col = p & 127;
            const int ng = n_base + col;
            if (ng >= N) continue;
            const float s0 = smf[j * 128 + col];
            const float s1 = smf[(j + 15) * 128 + col];
            const float mx = fmaxf(s0, s1);
            const float e0 = __expf(s0 - mx), e1 = __expf(s1 - mx);
            const float inv = 1.0f / (e0 + e1);
            const int b = ng / THW, rr = ng % THW;
            const long i0 = coff + ((long)(b * 30 + j)) * THW + rr;
            const long i1 = coff + ((long)(b * 30 + j + 15)) * THW + rr;
            if (f32) {
                ((float*)outv)[i0] = e0 * inv;
                ((float*)outv)[i1] = e1 * inv;
            } else {
                ((u16*)outv)[i0] = f2bf(e0 * inv);
                ((u16*)outv)[i1] = f2bf(e1 * inv);
            }
        }
    }
}

// ---------------------------------------------------------------- launcher
extern "C" void kernel_launch(void* const* d_in, const int* in_sizes, int n_in,
                              void* d_out, int out_size, void* d_ws, size_t ws_size,
                              hipStream_t stream)
{
    const void* base_feat = d_in[0];
    const u32*  im_info   = (const u32*)d_in[1];
    const void* W_conv    = d_in[4];
    const void* b_conv    = d_in[5];
    const void* W_cls     = d_in[6];
    const void* b_cls     = d_in[7];
    const void* W_bbox    = d_in[8];
    const void* b_bbox    = d_in[9];
    const void* W_bbox34  = d_in[10];
    const void* b_bbox34  = d_in[11];
    const void* W_bbox2   = d_in[12];
    const void* b_bbox2   = d_in[13];
    const void* W_bbox4   = d_in[14];
    const void* b_bbox4   = d_in[15];

    char* ws = (char*)d_ws;
    u16*   xpad = (u16*)  (ws + 0);           // 33,177,600
    u16*   wt   = (u16*)  (ws + 33177600);    // 14,155,776 -> 47,333,376
    u16*   y    = (u16*)  (ws + 47333376);    // 25,690,112 -> 73,023,488
    u16*   p4   = (u16*)  (ws + 73023488);    // 20,873,216 -> 93,896,704
    u16*   p8   = (u16*)  (ws + 93896704);    // 14,450,688 -> 108,347,392
    u16*   p12  = (u16*)  (ws + 108347392);   //  8,028,160 -> 116,375,552
    u16*   p16  = (u16*)  (ws + 116375552);   //  1,605,632 -> 117,981,184
    u16*   whd  = (u16*)  (ws + 123249728);   //  2,488,320 -> 125,738,048
    float* bfs  = (float*)(ws + 125738048);   //     11,768

    u16* w_cls_b  = whd;
    u16* w_b1_b   = whd + 15360;
    u16* w_b34_b  = whd + 506880;
    u16* w_b2_b   = whd + 875520;
    u16* w_b4_b   = whd + 1121280;

    pad_zero_fill<<<8996, 256, 0, stream>>>(base_feat, xpad, im_info);
    wt_cvt_all<<<5897, 256, 0, stream>>>(W_conv, wt,
                                         W_cls, W_bbox, W_bbox34, W_bbox2, W_bbox4,
                                         b_conv, b_cls, b_bbox, b_bbox34, b_bbox2,
                                         b_bbox4, whd, bfs, im_info);

    conv_gemm256<<<224, 512, 0, stream>>>(xpad, wt, bfs, y);

    pool_all<<<784, 256, 0, stream>>>(y, p4, p8, p12, p16);

    heads_gemm<<<1400, 256, 0, stream>>>(p16, p12, p8, p4,
                                         w_cls_b, w_b1_b, w_b34_b, w_b2_b, w_b4_b,
                                         bfs, d_out, im_info);
}